// Round 10
// baseline (1429.261 us; speedup 1.0000x reference)
//
#include <hip/hip_runtime.h>

#define NN 50000
#define NE 200000
#define NG 2048
#define D  512
#define H2 1024
#define NL 5
#define MPAD 50048   // 391 * 128

typedef __attribute__((ext_vector_type(8))) short bf16x8;
typedef __attribute__((ext_vector_type(4))) float f32x4;
typedef __attribute__((ext_vector_type(4))) int i32x4;
typedef __attribute__((ext_vector_type(4))) unsigned short u16x4;

__device__ __forceinline__ float bf2f(unsigned b) {
  union { unsigned u; float f; } c; c.u = b << 16; return c.f;
}
__device__ __forceinline__ unsigned short f2bf(float f) {
  union { float f; unsigned u; } c; c.f = f;
  return (unsigned short)((c.u + 0x7FFFu + ((c.u >> 16) & 1u)) >> 16);
}
__device__ __forceinline__ void add8(float* acc, uint4 v) {
  acc[0] += bf2f(v.x & 0xffffu); acc[1] += bf2f(v.x >> 16);
  acc[2] += bf2f(v.y & 0xffffu); acc[3] += bf2f(v.y >> 16);
  acc[4] += bf2f(v.z & 0xffffu); acc[5] += bf2f(v.z >> 16);
  acc[6] += bf2f(v.w & 0xffffu); acc[7] += bf2f(v.w >> 16);
}
__device__ __forceinline__ void addf8(float* acc, const float* p, float s) {
  float4 a = *(const float4*)p;
  float4 b = *(const float4*)(p + 4);
  acc[0] += s * a.x; acc[1] += s * a.y; acc[2] += s * a.z; acc[3] += s * a.w;
  acc[4] += s * b.x; acc[5] += s * b.y; acc[6] += s * b.z; acc[7] += s * b.w;
}
__device__ __forceinline__ uint4 pack8(const float* acc) {
  uint4 v;
  v.x = (unsigned)f2bf(acc[0]) | ((unsigned)f2bf(acc[1]) << 16);
  v.y = (unsigned)f2bf(acc[2]) | ((unsigned)f2bf(acc[3]) << 16);
  v.z = (unsigned)f2bf(acc[4]) | ((unsigned)f2bf(acc[5]) << 16);
  v.w = (unsigned)f2bf(acc[6]) | ((unsigned)f2bf(acc[7]) << 16);
  return v;
}
__device__ __forceinline__ void gload_lds16(const unsigned short* g, unsigned short* l) {
  __builtin_amdgcn_global_load_lds(
      (const __attribute__((address_space(1))) void*)g,
      (__attribute__((address_space(3))) void*)l, 16, 0, 0);
}
__device__ __forceinline__ void gload_lds16b(const signed char* g, signed char* l) {
  __builtin_amdgcn_global_load_lds(
      (const __attribute__((address_space(1))) void*)g,
      (__attribute__((address_space(3))) void*)l, 16, 0, 0);
}
__device__ __forceinline__ int q8(float v, float inv) {
  int q = (int)rintf(v * inv);
  if (q > 127) q = 127;
  if (q < -127) q = -127;
  return q;
}

// ---------------- atom encoder: h[n] = ae1[x0] + ae2[x1]  (bf16 out) ----------
__global__ void atom_enc_kernel(const int* __restrict__ x,
                                const float* __restrict__ ae1,
                                const float* __restrict__ ae2,
                                unsigned short* __restrict__ h) {
  int gid = blockIdx.x * 256 + threadIdx.x;
  int n = gid >> 6;
  if (n >= NN) return;
  int d0 = (gid & 63) << 3;
  int x0 = x[2 * n], x1 = x[2 * n + 1];
  float acc[8] = {0, 0, 0, 0, 0, 0, 0, 0};
  addf8(acc, ae1 + (size_t)x0 * D + d0, 1.0f);
  addf8(acc, ae2 + (size_t)x1 * D + d0, 1.0f);
  *(uint4*)(h + (size_t)n * D + d0) = pack8(acc);
}

// ---------------- CSR build ---------------------------------------------------
__global__ void count_kernel(const int* __restrict__ keys, int* __restrict__ cnt, int n) {
  int i = blockIdx.x * 256 + threadIdx.x;
  if (i < n) atomicAdd(&cnt[keys[i]], 1);
}

__global__ void exclusive_scan_kernel(const int* __restrict__ in, int* __restrict__ out, int n) {
  __shared__ int s[2][1024];
  int t = threadIdx.x;
  int C = (n + 1023) >> 10;
  int beg = t * C;
  int end = beg + C; if (end > n) end = n;
  if (beg > n) beg = n;
  int sum = 0;
  for (int i = beg; i < end; ++i) sum += in[i];
  s[0][t] = sum;
  __syncthreads();
  int pi = 0;
  for (int dd = 1; dd < 1024; dd <<= 1) {
    int v = s[pi][t];
    if (t >= dd) v += s[pi][t - dd];
    s[pi ^ 1][t] = v;
    pi ^= 1;
    __syncthreads();
  }
  int run = s[pi][t] - sum;
  for (int i = beg; i < end; ++i) { out[i] = run; run += in[i]; }
  if (t == 1023) out[n] = s[pi][1023];
}

__global__ void fill_csr_kernel(const int* __restrict__ ei, const int* __restrict__ ea,
                                const int* __restrict__ offs, int* __restrict__ cur,
                                int* __restrict__ packed) {
  int e = blockIdx.x * 256 + threadIdx.x;
  if (e >= NE) return;
  int dst = ei[NE + e];
  int pos = offs[dst] + atomicAdd(&cur[dst], 1);
  packed[pos] = (ei[e] & 0x1FFFF) | ((ea[2 * e] & 3) << 17) | ((ea[2 * e + 1] & 3) << 20);
}

// ---------------- aggregation + dynamic per-row i8 quantization ---------------
__global__ void agg_kernel(const unsigned short* __restrict__ h,
                           const int* __restrict__ offs,
                           const int* __restrict__ packed,
                           const float* __restrict__ be1,   // [8][512] layer slice
                           const float* __restrict__ be2,   // [4][512] layer slice
                           signed char* __restrict__ aq,    // [MPAD][512] i8
                           float* __restrict__ sa) {        // [MPAD] row scales
  int gid = blockIdx.x * 256 + threadIdx.x;
  int n = gid >> 6;
  if (n >= NN) return;
  int d0 = (gid & 63) << 3;
  float acc[8] = {0, 0, 0, 0, 0, 0, 0, 0};
  add8(acc, *(const uint4*)(h + (size_t)n * D + d0));
  addf8(acc, be1 + 6 * D + d0, 1.0f);
  addf8(acc, be2 + 3 * D + d0, 1.0f);
  int beg = offs[n], end = offs[n + 1];
  unsigned c0 = 0, c1 = 0;
  int i = beg;
  for (; i + 4 <= end; i += 4) {
    int p0 = packed[i], p1 = packed[i + 1], p2 = packed[i + 2], p3 = packed[i + 3];
    uint4 v0 = *(const uint4*)(h + (size_t)(p0 & 0x1FFFF) * D + d0);
    uint4 v1 = *(const uint4*)(h + (size_t)(p1 & 0x1FFFF) * D + d0);
    uint4 v2 = *(const uint4*)(h + (size_t)(p2 & 0x1FFFF) * D + d0);
    uint4 v3 = *(const uint4*)(h + (size_t)(p3 & 0x1FFFF) * D + d0);
    c0 += (1u << (((p0 >> 17) & 3) * 8)) + (1u << (((p1 >> 17) & 3) * 8)) +
          (1u << (((p2 >> 17) & 3) * 8)) + (1u << (((p3 >> 17) & 3) * 8));
    c1 += (1u << (((p0 >> 20) & 3) * 8)) + (1u << (((p1 >> 20) & 3) * 8)) +
          (1u << (((p2 >> 20) & 3) * 8)) + (1u << (((p3 >> 20) & 3) * 8));
    add8(acc, v0); add8(acc, v1); add8(acc, v2); add8(acc, v3);
  }
  for (; i < end; ++i) {
    int p = packed[i];
    c0 += 1u << (((p >> 17) & 3) * 8);
    c1 += 1u << (((p >> 20) & 3) * 8);
    add8(acc, *(const uint4*)(h + (size_t)(p & 0x1FFFF) * D + d0));
  }
  #pragma unroll
  for (int v = 0; v < 3; ++v) {
    float s0 = (float)((c0 >> (8 * v)) & 0xffu);
    float s1 = (float)((c1 >> (8 * v)) & 0xffu);
    if (s0 != 0.f) addf8(acc, be1 + v * D + d0, s0);
    if (s1 != 0.f) addf8(acc, be2 + v * D + d0, s1);
  }
  float mx = 0.f;
  #pragma unroll
  for (int j = 0; j < 8; ++j) mx = fmaxf(mx, fabsf(acc[j]));
  #pragma unroll
  for (int o = 32; o > 0; o >>= 1) mx = fmaxf(mx, __shfl_xor(mx, o));
  float s = mx * (1.0f / 127.0f);
  if (s < 1e-30f) s = 1e-30f;
  float inv = 1.0f / s;
  int q[8];
  #pragma unroll
  for (int j = 0; j < 8; ++j) q[j] = q8(acc[j], inv);
  uint2 pk;
  pk.x = (q[0] & 0xff) | ((q[1] & 0xff) << 8) | ((q[2] & 0xff) << 16) | ((q[3] & 0xff) << 24);
  pk.y = (q[4] & 0xff) | ((q[5] & 0xff) << 8) | ((q[6] & 0xff) << 16) | ((q[7] & 0xff) << 24);
  *(uint2*)(aq + (size_t)n * 512 + d0) = pk;
  if ((gid & 63) == 0) sa[n] = s;
}

// ---------------- mean pooling: one wave per graph ----------------------------
__global__ void pool_kernel(const unsigned short* __restrict__ h,
                            const int* __restrict__ goff,
                            unsigned short* __restrict__ pooled) {
  int gid = blockIdx.x * 256 + threadIdx.x;
  int g = gid >> 6;
  if (g >= NG) return;
  int d0 = (gid & 63) << 3;
  int beg = goff[g], end = goff[g + 1];
  float acc[8] = {0, 0, 0, 0, 0, 0, 0, 0};
  for (int nd = beg; nd < end; ++nd)
    add8(acc, *(const uint4*)(h + (size_t)nd * D + d0));
  int c = end - beg; if (c < 1) c = 1;
  float inv = 1.0f / (float)c;
  #pragma unroll
  for (int j = 0; j < 8; ++j) acc[j] *= inv;
  *(uint4*)(pooled + (size_t)g * D + d0) = pack8(acc);
}

// ---------------- f32 [R][C] -> bf16 [C][R] transpose (weights) ---------------
__global__ void transpose_bf16_kernel(const float* __restrict__ in,
                                      unsigned short* __restrict__ out,
                                      int R, int C) {
  __shared__ float tile[32][33];
  const float* inp = in + (size_t)blockIdx.z * R * C;
  unsigned short* outp = out + (size_t)blockIdx.z * R * C;
  int c0 = blockIdx.x * 32, r0 = blockIdx.y * 32;
  int tx = threadIdx.x, ty = threadIdx.y;  // (32, 8)
  #pragma unroll
  for (int j = 0; j < 32; j += 8)
    tile[ty + j][tx] = inp[(size_t)(r0 + ty + j) * C + (c0 + tx)];
  __syncthreads();
  #pragma unroll
  for (int j = 0; j < 32; j += 8)
    outp[(size_t)(c0 + ty + j) * R + (r0 + tx)] = f2bf(tile[tx][ty + j]);
}

// ---------------- W1 per-output-column absmax, split-K + atomicMax on bits ----
__global__ void wmax_kernel(const float* __restrict__ W, unsigned* __restrict__ swbits,
                            int K, int N) {
  int n = blockIdx.x * 256 + threadIdx.x;
  const float* Wl = W + (size_t)blockIdx.y * K * N;
  int kper = K / gridDim.z;
  int k0 = blockIdx.z * kper;
  float mx = 0.f;
  for (int k = k0; k < k0 + kper; ++k)
    mx = fmaxf(mx, fabsf(Wl[(size_t)k * N + n]));
  atomicMax(&swbits[(size_t)blockIdx.y * N + n], __float_as_uint(mx));
}

__global__ void scale_kernel(unsigned* __restrict__ swbits, int n) {
  int i = blockIdx.x * 256 + threadIdx.x;
  if (i >= n) return;
  float mx = __uint_as_float(swbits[i]);
  float s = mx * (1.0f / 127.0f);
  if (s < 1e-30f) s = 1e-30f;
  ((float*)swbits)[i] = s;
}

// ---------------- f32 [R][C] -> i8 [C][R] transpose + quant -------------------
__global__ void transpose_i8_kernel(const float* __restrict__ in,
                                    signed char* __restrict__ out,
                                    const float* __restrict__ sw,
                                    int R, int C) {
  __shared__ float tile[32][33];
  const float* inp = in + (size_t)blockIdx.z * R * C;
  signed char* outp = out + (size_t)blockIdx.z * R * C;
  const float* swp = sw + (size_t)blockIdx.z * C;
  int c0 = blockIdx.x * 32, r0 = blockIdx.y * 32;
  int tx = threadIdx.x, ty = threadIdx.y;  // (32, 8)
  #pragma unroll
  for (int j = 0; j < 32; j += 8)
    tile[ty + j][tx] = inp[(size_t)(r0 + ty + j) * C + (c0 + tx)];
  __syncthreads();
  #pragma unroll
  for (int j = 0; j < 32; j += 8) {
    int oc = c0 + ty + j;
    float inv = 1.0f / swp[oc];
    outp[(size_t)oc * R + (r0 + tx)] = (signed char)q8(tile[tx][ty + j], inv);
  }
}

// ---------------- NT bf16 MFMA GEMM (R6 K-loop + R9 LDS-staged C store) -------
__global__ __launch_bounds__(256) void gemm_nt(
    const unsigned short* __restrict__ A,
    const unsigned short* __restrict__ Bt,
    const float* __restrict__ bias,
    void* __restrict__ Cout,
    int K, int N, int gm, int gn, int relu, int out_f32) {
  __shared__ unsigned short SMEM[128 * 136];   // 34816 B
  unsigned short* Asm = SMEM;                  // 4096 elems
  unsigned short* Bsm = SMEM + 4096;           // 4096 elems
  const int tid = threadIdx.x;
  const int w = tid >> 6;
  const int lane = tid & 63;
  const int wm = w & 1, wn = w >> 1;

  int b = blockIdx.x;
  int band = b / (gn * 8);
  int r = b - band * (gn * 8);
  int bm = gm - band * 8; if (bm > 8) bm = 8;
  const long m0 = ((long)band * 8 + (r % bm)) * 128;
  const long n0 = (long)(r / bm) * 128;

  const unsigned short* Ag = A + (m0 + 32 * w + (lane >> 2)) * (long)K + (lane & 3) * 8;
  const unsigned short* Bg = Bt + (n0 + 32 * w + (lane >> 2)) * (long)K + (lane & 3) * 8;
  unsigned short* AsmW = Asm + 32 * w * 32;
  unsigned short* BsmW = Bsm + 32 * w * 32;
  const long rstep = 16l * K;

  const int frow = lane & 15;
  const int fcol = (lane >> 4) * 8;

  f32x4 acc[4][4];
  f32x4 zero = {0.f, 0.f, 0.f, 0.f};
  #pragma unroll
  for (int i = 0; i < 4; ++i)
    #pragma unroll
    for (int j = 0; j < 4; ++j) acc[i][j] = zero;

  for (int kt = 0; kt < K; kt += 32) {
    __syncthreads();
    gload_lds16(Ag + kt, AsmW);
    gload_lds16(Ag + kt + rstep, AsmW + 16 * 32);
    gload_lds16(Bg + kt, BsmW);
    gload_lds16(Bg + kt + rstep, BsmW + 16 * 32);
    __syncthreads();
    bf16x8 af[4], bfm[4];
    #pragma unroll
    for (int mt = 0; mt < 4; ++mt)
      af[mt] = *(const bf16x8*)(Asm + (wm * 64 + mt * 16 + frow) * 32 + fcol);
    #pragma unroll
    for (int nt = 0; nt < 4; ++nt)
      bfm[nt] = *(const bf16x8*)(Bsm + (wn * 64 + nt * 16 + frow) * 32 + fcol);
    #pragma unroll
    for (int mt = 0; mt < 4; ++mt)
      #pragma unroll
      for (int nt = 0; nt < 4; ++nt)
        acc[mt][nt] = __builtin_amdgcn_mfma_f32_16x16x32_bf16(bfm[nt], af[mt], acc[mt][nt], 0, 0, 0);
  }

  const int nq = (lane >> 4) * 4;
  if (out_f32) {
    #pragma unroll
    for (int mt = 0; mt < 4; ++mt) {
      long gm_ = m0 + wm * 64 + mt * 16 + frow;
      #pragma unroll
      for (int nt = 0; nt < 4; ++nt) {
        long gn_ = n0 + wn * 64 + nt * 16 + nq;
        float4 bv = *(const float4*)(bias + gn_);
        float v0 = acc[mt][nt][0] + bv.x;
        float v1 = acc[mt][nt][1] + bv.y;
        float v2 = acc[mt][nt][2] + bv.z;
        float v3 = acc[mt][nt][3] + bv.w;
        if (relu) {
          v0 = fmaxf(v0, 0.f); v1 = fmaxf(v1, 0.f);
          v2 = fmaxf(v2, 0.f); v3 = fmaxf(v3, 0.f);
        }
        float4 o = {v0, v1, v2, v3};
        *(float4*)((float*)Cout + gm_ * (long)N + gn_) = o;
      }
    }
  } else {
    __syncthreads();   // staging LDS no longer needed; reuse as C tile
    #pragma unroll
    for (int mt = 0; mt < 4; ++mt) {
      int ml = wm * 64 + mt * 16 + frow;
      #pragma unroll
      for (int nt = 0; nt < 4; ++nt) {
        int nl = wn * 64 + nt * 16 + nq;
        float4 bv = *(const float4*)(bias + n0 + nl);
        float v0 = acc[mt][nt][0] + bv.x;
        float v1 = acc[mt][nt][1] + bv.y;
        float v2 = acc[mt][nt][2] + bv.z;
        float v3 = acc[mt][nt][3] + bv.w;
        if (relu) {
          v0 = fmaxf(v0, 0.f); v1 = fmaxf(v1, 0.f);
          v2 = fmaxf(v2, 0.f); v3 = fmaxf(v3, 0.f);
        }
        u16x4 o = {f2bf(v0), f2bf(v1), f2bf(v2), f2bf(v3)};
        *(u16x4*)(SMEM + ml * 136 + nl) = o;
      }
    }
    __syncthreads();
    unsigned short* Cg = (unsigned short*)Cout;
    #pragma unroll
    for (int p = 0; p < 8; ++p) {
      int row = p * 16 + (tid >> 4);
      int col = (tid & 15) * 8;
      uint4 v = *(const uint4*)(SMEM + row * 136 + col);
      *(uint4*)(Cg + (m0 + row) * (long)N + n0 + col) = v;
    }
  }
}

// ---------------- NT i8 MFMA GEMM (16x16x64_i8, BK=64, LDS-staged C store) ----
__global__ __launch_bounds__(256) void gemm_nt_i8(
    const signed char* __restrict__ A,   // [M][K] i8
    const signed char* __restrict__ Bt,  // [N][K] i8
    const float* __restrict__ sa,        // [M]
    const float* __restrict__ sb,        // [N]
    const float* __restrict__ bias,      // [N]
    unsigned short* __restrict__ Cout,
    int K, int N, int gm, int gn, int relu) {
  __shared__ unsigned short SMEM[128 * 136];   // 34816 B (staging uses first 16KB)
  signed char* Asm = (signed char*)SMEM;       // 8192 B
  signed char* Bsm = Asm + 8192;               // 8192 B
  const int tid = threadIdx.x;
  const int w = tid >> 6;
  const int lane = tid & 63;
  const int wm = w & 1, wn = w >> 1;

  int b = blockIdx.x;
  int band = b / (gn * 8);
  int r = b - band * (gn * 8);
  int bm = gm - band * 8; if (bm > 8) bm = 8;
  const long m0 = ((long)band * 8 + (r % bm)) * 128;
  const long n0 = (long)(r / bm) * 128;

  const signed char* Ag = A + (m0 + 32 * w + (lane >> 2)) * (long)K + (lane & 3) * 16;
  const signed char* Bg = Bt + (n0 + 32 * w + (lane >> 2)) * (long)K + (lane & 3) * 16;
  signed char* AsmW = Asm + 32 * w * 64;
  signed char* BsmW = Bsm + 32 * w * 64;
  const long rstep = 16l * K;

  const int frow = lane & 15;
  const int fcol = (lane >> 4) * 16;

  i32x4 acc[4][4];
  i32x4 zero = {0, 0, 0, 0};
  #pragma unroll
  for (int i = 0; i < 4; ++i)
    #pragma unroll
    for (int j = 0; j < 4; ++j) acc[i][j] = zero;

  for (int kt = 0; kt < K; kt += 64) {
    __syncthreads();
    gload_lds16b(Ag + kt, AsmW);
    gload_lds16b(Ag + kt + rstep, AsmW + 16 * 64);
    gload_lds16b(Bg + kt, BsmW);
    gload_lds16b(Bg + kt + rstep, BsmW + 16 * 64);
    __syncthreads();
    i32x4 af[4], bfm[4];
    #pragma unroll
    for (int mt = 0; mt < 4; ++mt)
      af[mt] = *(const i32x4*)(Asm + (wm * 64 + mt * 16 + frow) * 64 + fcol);
    #pragma unroll
    for (int nt = 0; nt < 4; ++nt)
      bfm[nt] = *(const i32x4*)(Bsm + (wn * 64 + nt * 16 + frow) * 64 + fcol);
    #pragma unroll
    for (int mt = 0; mt < 4; ++mt)
      #pragma unroll
      for (int nt = 0; nt < 4; ++nt)
        acc[mt][nt] = __builtin_amdgcn_mfma_i32_16x16x64_i8(bfm[nt], af[mt], acc[mt][nt], 0, 0, 0);
  }

  const int nq = (lane >> 4) * 4;
  __syncthreads();   // staging LDS no longer needed; reuse as C tile
  #pragma unroll
  for (int mt = 0; mt < 4; ++mt) {
    int ml = wm * 64 + mt * 16 + frow;
    float sam = sa[m0 + ml];
    #pragma unroll
    for (int nt = 0; nt < 4; ++nt) {
      int nl = wn * 64 + nt * 16 + nq;
      float4 bv = *(const float4*)(bias + n0 + nl);
      float4 sbv = *(const float4*)(sb + n0 + nl);
      float v0 = (float)acc[mt][nt][0] * (sam * sbv.x) + bv.x;
      float v1 = (float)acc[mt][nt][1] * (sam * sbv.y) + bv.y;
      float v2 = (float)acc[mt][nt][2] * (sam * sbv.z) + bv.z;
      float v3 = (float)acc[mt][nt][3] * (sam * sbv.w) + bv.w;
      if (relu) {
        v0 = fmaxf(v0, 0.f); v1 = fmaxf(v1, 0.f);
        v2 = fmaxf(v2, 0.f); v3 = fmaxf(v3, 0.f);
      }
      u16x4 o = {f2bf(v0), f2bf(v1), f2bf(v2), f2bf(v3)};
      *(u16x4*)(SMEM + ml * 136 + nl) = o;
    }
  }
  __syncthreads();
  #pragma unroll
  for (int p = 0; p < 8; ++p) {
    int row = p * 16 + (tid >> 4);
    int col = (tid & 15) * 8;
    uint4 v = *(const uint4*)(SMEM + row * 136 + col);
    *(uint4*)(Cout + (m0 + row) * (long)N + n0 + col) = v;
  }
}

extern "C" void kernel_launch(void* const* d_in, const int* in_sizes, int n_in,
                              void* d_out, int out_size, void* d_ws, size_t ws_size,
                              hipStream_t stream) {
  (void)in_sizes; (void)n_in; (void)out_size; (void)ws_size;
  const int*   x          = (const int*)d_in[0];
  const int*   edge_index = (const int*)d_in[1];
  const int*   edge_attr  = (const int*)d_in[2];
  const int*   batch      = (const int*)d_in[3];
  const float* atom_emb1  = (const float*)d_in[4];
  const float* atom_emb2  = (const float*)d_in[5];
  const float* bond_emb1  = (const float*)d_in[6];   // [5][8][512]
  const float* bond_emb2  = (const float*)d_in[7];   // [5][4][512]
  const float* W1         = (const float*)d_in[8];   // [5][512][1024]
  const float* b1         = (const float*)d_in[9];   // [5][1024]
  const float* W2         = (const float*)d_in[10];  // [5][1024][512]
  const float* b2         = (const float*)d_in[11];  // [5][512]
  const float* pW1        = (const float*)d_in[12];  // [512][512]
  const float* pb1        = (const float*)d_in[13];
  const float* pW2        = (const float*)d_in[14];
  const float* pb2        = (const float*)d_in[15];

  // ---- workspace layout ----
  unsigned short* h      = (unsigned short*)d_ws;                 // MPAD*D bf16
  unsigned short* hidden = h + (size_t)MPAD * D;                  // chunked: 196*128*H2 bf16
  unsigned short* w2t    = hidden + (size_t)MPAD * H2;            // NL*D*H2 bf16
  unsigned short* pw1t   = w2t + (size_t)NL * D * H2;             // D*D
  unsigned short* pw2t   = pw1t + (size_t)D * D;                  // D*D
  unsigned short* pooled = pw2t + (size_t)D * D;                  // NG*D
  unsigned short* zmid   = pooled + (size_t)NG * D;               // NG*D
  signed char* aq  = (signed char*)(zmid + (size_t)NG * D);       // MPAD*512 i8
  signed char* w1q = aq + (size_t)MPAD * 512;                     // NL*H2*512 i8
  float* sa  = (float*)(w1q + (size_t)NL * H2 * 512);             // MPAD
  float* sw1 = sa + MPAD;                                         // NL*H2 (zero-init)
  int* indeg  = (int*)(sw1 + NL * H2);                            // NN+1 (zero-init)
  int* cur    = indeg + (NN + 1);                                 // NN   (zero-init)
  int* gcnt   = cur + NN;                                         // NG   (zero-init)
  int* offs   = gcnt + NG;                                        // NN+1
  int* goff   = offs + (NN + 1);                                  // NG+1
  int* packed = goff + (NG + 1);                                  // NE

  // zero sw1 (absmax accum) + counters in one memset (adjacent)
  (void)hipMemsetAsync(sw1, 0, ((size_t)NL * H2 + (NN + 1) + NN + NG) * 4, stream);

  // W1 -> i8 [n][k] + per-col scales (split-K absmax, bit-pattern atomicMax)
  wmax_kernel<<<dim3(H2 / 256, NL, 16), 256, 0, stream>>>(W1, (unsigned*)sw1, D, H2);
  scale_kernel<<<(NL * H2 + 255) / 256, 256, 0, stream>>>((unsigned*)sw1, NL * H2);
  transpose_i8_kernel<<<dim3(H2 / 32, D / 32, NL), dim3(32, 8), 0, stream>>>(W1, w1q, sw1, D, H2);
  transpose_bf16_kernel<<<dim3(D / 32, H2 / 32, NL), dim3(32, 8), 0, stream>>>(W2, w2t, H2, D);
  transpose_bf16_kernel<<<dim3(D / 32, D / 32, 1), dim3(32, 8), 0, stream>>>(pW1, pw1t, D, D);
  transpose_bf16_kernel<<<dim3(D / 32, D / 32, 1), dim3(32, 8), 0, stream>>>(pW2, pw2t, D, D);

  atom_enc_kernel<<<(NN * 64) / 256, 256, 0, stream>>>(x, atom_emb1, atom_emb2, h);

  count_kernel<<<(NE + 255) / 256, 256, 0, stream>>>(edge_index + NE, indeg, NE);
  exclusive_scan_kernel<<<1, 1024, 0, stream>>>(indeg, offs, NN);
  fill_csr_kernel<<<(NE + 255) / 256, 256, 0, stream>>>(edge_index, edge_attr, offs, cur, packed);

  count_kernel<<<(NN + 255) / 256, 256, 0, stream>>>(batch, gcnt, NN);
  exclusive_scan_kernel<<<1, 1024, 0, stream>>>(gcnt, goff, NG);

  // M-chunking: interleave GEMM1(c) -> GEMM2(c) so the 51 MB hidden chunk is
  // consumed while L3-resident (R9 counters: GEMM2 FETCH 63 MB = hidden falling
  // out of L3 between producer and consumer). Both chunks share one buffer so
  // chunk 1 overwrites chunk 0's dirty lines before eviction.
  const int GMC[2] = {196, 195};  // 196+195 = 391 = MPAD/128
  for (int l = 0; l < NL; ++l) {
    agg_kernel<<<(NN * 64) / 256, 256, 0, stream>>>(
        h, offs, packed, bond_emb1 + (size_t)l * 8 * D, bond_emb2 + (size_t)l * 4 * D, aq, sa);
    long moff = 0;
    for (int c = 0; c < 2; ++c) {
      const int gmc = GMC[c];
      gemm_nt_i8<<<gmc * (H2 / 128), 256, 0, stream>>>(
          aq + moff * 512, w1q + (size_t)l * H2 * 512, sa + moff,
          sw1 + (size_t)l * H2, b1 + (size_t)l * H2,
          hidden, D, H2, gmc, H2 / 128, 1);
      gemm_nt<<<gmc * (D / 128), 256, 0, stream>>>(
          hidden, w2t + (size_t)l * D * H2, b2 + (size_t)l * D, h + moff * D,
          H2, D, gmc, D / 128, (l < NL - 1) ? 1 : 0, 0);
      moff += (long)gmc * 128;
    }
  }

  pool_kernel<<<(NG * 64) / 256, 256, 0, stream>>>(h, goff, pooled);
  gemm_nt<<<(NG / 128) * (D / 128), 256, 0, stream>>>(
      pooled, pw1t, pb1, zmid, D, D, NG / 128, D / 128, 1, 0);
  gemm_nt<<<(NG / 128) * (D / 128), 256, 0, stream>>>(
      zmid, pw2t, pb2, (float*)d_out, D, D, NG / 128, D / 128, 0, 1);
}

// Round 11
// 1197.012 us; speedup vs baseline: 1.1940x; 1.1940x over previous
//
#include <hip/hip_runtime.h>

#define NN 50000
#define NE 200000
#define NG 2048
#define D  512
#define H2 1024
#define NL 5
#define MPAD 50048   // 391 * 128

typedef __attribute__((ext_vector_type(8))) short bf16x8;
typedef __attribute__((ext_vector_type(4))) float f32x4;
typedef __attribute__((ext_vector_type(4))) int i32x4;
typedef __attribute__((ext_vector_type(4))) unsigned short u16x4;

__device__ __forceinline__ float bf2f(unsigned b) {
  union { unsigned u; float f; } c; c.u = b << 16; return c.f;
}
__device__ __forceinline__ unsigned short f2bf(float f) {
  union { float f; unsigned u; } c; c.f = f;
  return (unsigned short)((c.u + 0x7FFFu + ((c.u >> 16) & 1u)) >> 16);
}
__device__ __forceinline__ void add8(float* acc, uint4 v) {
  acc[0] += bf2f(v.x & 0xffffu); acc[1] += bf2f(v.x >> 16);
  acc[2] += bf2f(v.y & 0xffffu); acc[3] += bf2f(v.y >> 16);
  acc[4] += bf2f(v.z & 0xffffu); acc[5] += bf2f(v.z >> 16);
  acc[6] += bf2f(v.w & 0xffffu); acc[7] += bf2f(v.w >> 16);
}
__device__ __forceinline__ void addf8(float* acc, const float* p, float s) {
  float4 a = *(const float4*)p;
  float4 b = *(const float4*)(p + 4);
  acc[0] += s * a.x; acc[1] += s * a.y; acc[2] += s * a.z; acc[3] += s * a.w;
  acc[4] += s * b.x; acc[5] += s * b.y; acc[6] += s * b.z; acc[7] += s * b.w;
}
__device__ __forceinline__ uint4 pack8(const float* acc) {
  uint4 v;
  v.x = (unsigned)f2bf(acc[0]) | ((unsigned)f2bf(acc[1]) << 16);
  v.y = (unsigned)f2bf(acc[2]) | ((unsigned)f2bf(acc[3]) << 16);
  v.z = (unsigned)f2bf(acc[4]) | ((unsigned)f2bf(acc[5]) << 16);
  v.w = (unsigned)f2bf(acc[6]) | ((unsigned)f2bf(acc[7]) << 16);
  return v;
}
__device__ __forceinline__ void gload_lds16(const unsigned short* g, unsigned short* l) {
  __builtin_amdgcn_global_load_lds(
      (const __attribute__((address_space(1))) void*)g,
      (__attribute__((address_space(3))) void*)l, 16, 0, 0);
}
__device__ __forceinline__ void gload_lds16b(const signed char* g, signed char* l) {
  __builtin_amdgcn_global_load_lds(
      (const __attribute__((address_space(1))) void*)g,
      (__attribute__((address_space(3))) void*)l, 16, 0, 0);
}
__device__ __forceinline__ int q8(float v, float inv) {
  int q = (int)rintf(v * inv);
  if (q > 127) q = 127;
  if (q < -127) q = -127;
  return q;
}

// ---------------- atom encoder: h[n] = ae1[x0] + ae2[x1]  (bf16 out) ----------
__global__ void atom_enc_kernel(const int* __restrict__ x,
                                const float* __restrict__ ae1,
                                const float* __restrict__ ae2,
                                unsigned short* __restrict__ h) {
  int gid = blockIdx.x * 256 + threadIdx.x;
  int n = gid >> 6;
  if (n >= NN) return;
  int d0 = (gid & 63) << 3;
  int x0 = x[2 * n], x1 = x[2 * n + 1];
  float acc[8] = {0, 0, 0, 0, 0, 0, 0, 0};
  addf8(acc, ae1 + (size_t)x0 * D + d0, 1.0f);
  addf8(acc, ae2 + (size_t)x1 * D + d0, 1.0f);
  *(uint4*)(h + (size_t)n * D + d0) = pack8(acc);
}

// ---------------- CSR build ---------------------------------------------------
__global__ void count_kernel(const int* __restrict__ keys, int* __restrict__ cnt, int n) {
  int i = blockIdx.x * 256 + threadIdx.x;
  if (i < n) atomicAdd(&cnt[keys[i]], 1);
}

// ---- 3-phase multi-block exclusive scan (4096 elems/block, int4-coalesced) ---
__global__ void scan_sums_kernel(const int* __restrict__ in, int* __restrict__ bsum, int n) {
  __shared__ int sm[1024];
  int t = threadIdx.x;
  int base = blockIdx.x * 4096 + t * 4;
  int s = 0;
  if (base + 3 < n) {
    int4 v = *(const int4*)(in + base);
    s = v.x + v.y + v.z + v.w;
  } else {
    for (int i = 0; i < 4; ++i) if (base + i < n) s += in[base + i];
  }
  sm[t] = s;
  __syncthreads();
  for (int d = 512; d > 0; d >>= 1) {
    if (t < d) sm[t] += sm[t + d];
    __syncthreads();
  }
  if (t == 0) bsum[blockIdx.x] = sm[0];
}

__global__ void scan_partials_kernel(int* __restrict__ bsum, int B) {
  if (threadIdx.x == 0 && blockIdx.x == 0) {
    int run = 0;
    for (int i = 0; i < B; ++i) { int v = bsum[i]; bsum[i] = run; run += v; }
    bsum[B] = run;
  }
}

__global__ void scan_final_kernel(const int* __restrict__ in, const int* __restrict__ bsum,
                                  int* __restrict__ out, int n) {
  __shared__ int sm[2][1024];
  int t = threadIdx.x;
  int base = blockIdx.x * 4096 + t * 4;
  int v0 = 0, v1 = 0, v2 = 0, v3 = 0;
  if (base + 3 < n) {
    int4 v = *(const int4*)(in + base);
    v0 = v.x; v1 = v.y; v2 = v.z; v3 = v.w;
  } else {
    if (base + 0 < n) v0 = in[base + 0];
    if (base + 1 < n) v1 = in[base + 1];
    if (base + 2 < n) v2 = in[base + 2];
    if (base + 3 < n) v3 = in[base + 3];
  }
  int local = v0 + v1 + v2 + v3;
  sm[0][t] = local;
  __syncthreads();
  int pi = 0;
  for (int dd = 1; dd < 1024; dd <<= 1) {
    int v = sm[pi][t];
    if (t >= dd) v += sm[pi][t - dd];
    sm[pi ^ 1][t] = v;
    pi ^= 1;
    __syncthreads();
  }
  int pre = sm[pi][t] - local + bsum[blockIdx.x];
  if (base + 3 < n) {
    int4 o; o.x = pre; o.y = pre + v0; o.z = pre + v0 + v1; o.w = pre + v0 + v1 + v2;
    *(int4*)(out + base) = o;
  } else {
    if (base + 0 < n) out[base + 0] = pre;
    if (base + 1 < n) out[base + 1] = pre + v0;
    if (base + 2 < n) out[base + 2] = pre + v0 + v1;
    if (base + 3 < n) out[base + 3] = pre + v0 + v1 + v2;
  }
  if (blockIdx.x == 0 && t == 0) out[n] = bsum[gridDim.x];
}

__global__ void fill_csr_kernel(const int* __restrict__ ei, const int* __restrict__ ea,
                                const int* __restrict__ offs, int* __restrict__ cur,
                                int* __restrict__ packed) {
  int e = blockIdx.x * 256 + threadIdx.x;
  if (e >= NE) return;
  int dst = ei[NE + e];
  int pos = offs[dst] + atomicAdd(&cur[dst], 1);
  packed[pos] = (ei[e] & 0x1FFFF) | ((ea[2 * e] & 3) << 17) | ((ea[2 * e + 1] & 3) << 20);
}

// ---------------- aggregation + dynamic per-row i8 quantization ---------------
__global__ void agg_kernel(const unsigned short* __restrict__ h,
                           const int* __restrict__ offs,
                           const int* __restrict__ packed,
                           const float* __restrict__ be1,   // [8][512] layer slice
                           const float* __restrict__ be2,   // [4][512] layer slice
                           signed char* __restrict__ aq,    // [MPAD][512] i8
                           float* __restrict__ sa) {        // [MPAD] row scales
  int gid = blockIdx.x * 256 + threadIdx.x;
  int n = gid >> 6;
  if (n >= NN) return;
  int d0 = (gid & 63) << 3;
  float acc[8] = {0, 0, 0, 0, 0, 0, 0, 0};
  add8(acc, *(const uint4*)(h + (size_t)n * D + d0));
  addf8(acc, be1 + 6 * D + d0, 1.0f);
  addf8(acc, be2 + 3 * D + d0, 1.0f);
  int beg = offs[n], end = offs[n + 1];
  unsigned c0 = 0, c1 = 0;
  int i = beg;
  for (; i + 4 <= end; i += 4) {
    int p0 = packed[i], p1 = packed[i + 1], p2 = packed[i + 2], p3 = packed[i + 3];
    uint4 v0 = *(const uint4*)(h + (size_t)(p0 & 0x1FFFF) * D + d0);
    uint4 v1 = *(const uint4*)(h + (size_t)(p1 & 0x1FFFF) * D + d0);
    uint4 v2 = *(const uint4*)(h + (size_t)(p2 & 0x1FFFF) * D + d0);
    uint4 v3 = *(const uint4*)(h + (size_t)(p3 & 0x1FFFF) * D + d0);
    c0 += (1u << (((p0 >> 17) & 3) * 8)) + (1u << (((p1 >> 17) & 3) * 8)) +
          (1u << (((p2 >> 17) & 3) * 8)) + (1u << (((p3 >> 17) & 3) * 8));
    c1 += (1u << (((p0 >> 20) & 3) * 8)) + (1u << (((p1 >> 20) & 3) * 8)) +
          (1u << (((p2 >> 20) & 3) * 8)) + (1u << (((p3 >> 20) & 3) * 8));
    add8(acc, v0); add8(acc, v1); add8(acc, v2); add8(acc, v3);
  }
  for (; i < end; ++i) {
    int p = packed[i];
    c0 += 1u << (((p >> 17) & 3) * 8);
    c1 += 1u << (((p >> 20) & 3) * 8);
    add8(acc, *(const uint4*)(h + (size_t)(p & 0x1FFFF) * D + d0));
  }
  #pragma unroll
  for (int v = 0; v < 3; ++v) {
    float s0 = (float)((c0 >> (8 * v)) & 0xffu);
    float s1 = (float)((c1 >> (8 * v)) & 0xffu);
    if (s0 != 0.f) addf8(acc, be1 + v * D + d0, s0);
    if (s1 != 0.f) addf8(acc, be2 + v * D + d0, s1);
  }
  float mx = 0.f;
  #pragma unroll
  for (int j = 0; j < 8; ++j) mx = fmaxf(mx, fabsf(acc[j]));
  #pragma unroll
  for (int o = 32; o > 0; o >>= 1) mx = fmaxf(mx, __shfl_xor(mx, o));
  float s = mx * (1.0f / 127.0f);
  if (s < 1e-30f) s = 1e-30f;
  float inv = 1.0f / s;
  int q[8];
  #pragma unroll
  for (int j = 0; j < 8; ++j) q[j] = q8(acc[j], inv);
  uint2 pk;
  pk.x = (q[0] & 0xff) | ((q[1] & 0xff) << 8) | ((q[2] & 0xff) << 16) | ((q[3] & 0xff) << 24);
  pk.y = (q[4] & 0xff) | ((q[5] & 0xff) << 8) | ((q[6] & 0xff) << 16) | ((q[7] & 0xff) << 24);
  *(uint2*)(aq + (size_t)n * 512 + d0) = pk;
  if ((gid & 63) == 0) sa[n] = s;
}

// ---------------- mean pooling: one wave per graph ----------------------------
__global__ void pool_kernel(const unsigned short* __restrict__ h,
                            const int* __restrict__ goff,
                            unsigned short* __restrict__ pooled) {
  int gid = blockIdx.x * 256 + threadIdx.x;
  int g = gid >> 6;
  if (g >= NG) return;
  int d0 = (gid & 63) << 3;
  int beg = goff[g], end = goff[g + 1];
  float acc[8] = {0, 0, 0, 0, 0, 0, 0, 0};
  for (int nd = beg; nd < end; ++nd)
    add8(acc, *(const uint4*)(h + (size_t)nd * D + d0));
  int c = end - beg; if (c < 1) c = 1;
  float inv = 1.0f / (float)c;
  #pragma unroll
  for (int j = 0; j < 8; ++j) acc[j] *= inv;
  *(uint4*)(pooled + (size_t)g * D + d0) = pack8(acc);
}

// ---------------- f32 [R][C] -> bf16 [C][R] transpose (weights) ---------------
__global__ void transpose_bf16_kernel(const float* __restrict__ in,
                                      unsigned short* __restrict__ out,
                                      int R, int C) {
  __shared__ float tile[32][33];
  const float* inp = in + (size_t)blockIdx.z * R * C;
  unsigned short* outp = out + (size_t)blockIdx.z * R * C;
  int c0 = blockIdx.x * 32, r0 = blockIdx.y * 32;
  int tx = threadIdx.x, ty = threadIdx.y;  // (32, 8)
  #pragma unroll
  for (int j = 0; j < 32; j += 8)
    tile[ty + j][tx] = inp[(size_t)(r0 + ty + j) * C + (c0 + tx)];
  __syncthreads();
  #pragma unroll
  for (int j = 0; j < 32; j += 8)
    outp[(size_t)(c0 + ty + j) * R + (r0 + tx)] = f2bf(tile[tx][ty + j]);
}

// ---------------- W1 per-output-column absmax, split-K + atomicMax on bits ----
__global__ void wmax_kernel(const float* __restrict__ W, unsigned* __restrict__ swbits,
                            int K, int N) {
  int n = blockIdx.x * 256 + threadIdx.x;
  const float* Wl = W + (size_t)blockIdx.y * K * N;
  int kper = K / gridDim.z;
  int k0 = blockIdx.z * kper;
  float mx = 0.f;
  for (int k = k0; k < k0 + kper; ++k)
    mx = fmaxf(mx, fabsf(Wl[(size_t)k * N + n]));
  atomicMax(&swbits[(size_t)blockIdx.y * N + n], __float_as_uint(mx));
}

__global__ void scale_kernel(unsigned* __restrict__ swbits, int n) {
  int i = blockIdx.x * 256 + threadIdx.x;
  if (i >= n) return;
  float mx = __uint_as_float(swbits[i]);
  float s = mx * (1.0f / 127.0f);
  if (s < 1e-30f) s = 1e-30f;
  ((float*)swbits)[i] = s;
}

// ---------------- f32 [R][C] -> i8 [C][R] transpose + quant -------------------
__global__ void transpose_i8_kernel(const float* __restrict__ in,
                                    signed char* __restrict__ out,
                                    const float* __restrict__ sw,
                                    int R, int C) {
  __shared__ float tile[32][33];
  const float* inp = in + (size_t)blockIdx.z * R * C;
  signed char* outp = out + (size_t)blockIdx.z * R * C;
  const float* swp = sw + (size_t)blockIdx.z * C;
  int c0 = blockIdx.x * 32, r0 = blockIdx.y * 32;
  int tx = threadIdx.x, ty = threadIdx.y;  // (32, 8)
  #pragma unroll
  for (int j = 0; j < 32; j += 8)
    tile[ty + j][tx] = inp[(size_t)(r0 + ty + j) * C + (c0 + tx)];
  __syncthreads();
  #pragma unroll
  for (int j = 0; j < 32; j += 8) {
    int oc = c0 + ty + j;
    float inv = 1.0f / swp[oc];
    outp[(size_t)oc * R + (r0 + tx)] = (signed char)q8(tile[tx][ty + j], inv);
  }
}

// ---------------- NT bf16 MFMA GEMM (R6 K-loop + R9 LDS-staged C store) -------
__global__ __launch_bounds__(256) void gemm_nt(
    const unsigned short* __restrict__ A,
    const unsigned short* __restrict__ Bt,
    const float* __restrict__ bias,
    void* __restrict__ Cout,
    int K, int N, int gm, int gn, int relu, int out_f32) {
  __shared__ unsigned short SMEM[128 * 136];   // 34816 B
  unsigned short* Asm = SMEM;                  // 4096 elems
  unsigned short* Bsm = SMEM + 4096;           // 4096 elems
  const int tid = threadIdx.x;
  const int w = tid >> 6;
  const int lane = tid & 63;
  const int wm = w & 1, wn = w >> 1;

  int b = blockIdx.x;
  int band = b / (gn * 8);
  int r = b - band * (gn * 8);
  int bm = gm - band * 8; if (bm > 8) bm = 8;
  const long m0 = ((long)band * 8 + (r % bm)) * 128;
  const long n0 = (long)(r / bm) * 128;

  const unsigned short* Ag = A + (m0 + 32 * w + (lane >> 2)) * (long)K + (lane & 3) * 8;
  const unsigned short* Bg = Bt + (n0 + 32 * w + (lane >> 2)) * (long)K + (lane & 3) * 8;
  unsigned short* AsmW = Asm + 32 * w * 32;
  unsigned short* BsmW = Bsm + 32 * w * 32;
  const long rstep = 16l * K;

  const int frow = lane & 15;
  const int fcol = (lane >> 4) * 8;

  f32x4 acc[4][4];
  f32x4 zero = {0.f, 0.f, 0.f, 0.f};
  #pragma unroll
  for (int i = 0; i < 4; ++i)
    #pragma unroll
    for (int j = 0; j < 4; ++j) acc[i][j] = zero;

  for (int kt = 0; kt < K; kt += 32) {
    __syncthreads();
    gload_lds16(Ag + kt, AsmW);
    gload_lds16(Ag + kt + rstep, AsmW + 16 * 32);
    gload_lds16(Bg + kt, BsmW);
    gload_lds16(Bg + kt + rstep, BsmW + 16 * 32);
    __syncthreads();
    bf16x8 af[4], bfm[4];
    #pragma unroll
    for (int mt = 0; mt < 4; ++mt)
      af[mt] = *(const bf16x8*)(Asm + (wm * 64 + mt * 16 + frow) * 32 + fcol);
    #pragma unroll
    for (int nt = 0; nt < 4; ++nt)
      bfm[nt] = *(const bf16x8*)(Bsm + (wn * 64 + nt * 16 + frow) * 32 + fcol);
    #pragma unroll
    for (int mt = 0; mt < 4; ++mt)
      #pragma unroll
      for (int nt = 0; nt < 4; ++nt)
        acc[mt][nt] = __builtin_amdgcn_mfma_f32_16x16x32_bf16(bfm[nt], af[mt], acc[mt][nt], 0, 0, 0);
  }

  const int nq = (lane >> 4) * 4;
  if (out_f32) {
    #pragma unroll
    for (int mt = 0; mt < 4; ++mt) {
      long gm_ = m0 + wm * 64 + mt * 16 + frow;
      #pragma unroll
      for (int nt = 0; nt < 4; ++nt) {
        long gn_ = n0 + wn * 64 + nt * 16 + nq;
        float4 bv = *(const float4*)(bias + gn_);
        float v0 = acc[mt][nt][0] + bv.x;
        float v1 = acc[mt][nt][1] + bv.y;
        float v2 = acc[mt][nt][2] + bv.z;
        float v3 = acc[mt][nt][3] + bv.w;
        if (relu) {
          v0 = fmaxf(v0, 0.f); v1 = fmaxf(v1, 0.f);
          v2 = fmaxf(v2, 0.f); v3 = fmaxf(v3, 0.f);
        }
        float4 o = {v0, v1, v2, v3};
        *(float4*)((float*)Cout + gm_ * (long)N + gn_) = o;
      }
    }
  } else {
    __syncthreads();   // staging LDS no longer needed; reuse as C tile
    #pragma unroll
    for (int mt = 0; mt < 4; ++mt) {
      int ml = wm * 64 + mt * 16 + frow;
      #pragma unroll
      for (int nt = 0; nt < 4; ++nt) {
        int nl = wn * 64 + nt * 16 + nq;
        float4 bv = *(const float4*)(bias + n0 + nl);
        float v0 = acc[mt][nt][0] + bv.x;
        float v1 = acc[mt][nt][1] + bv.y;
        float v2 = acc[mt][nt][2] + bv.z;
        float v3 = acc[mt][nt][3] + bv.w;
        if (relu) {
          v0 = fmaxf(v0, 0.f); v1 = fmaxf(v1, 0.f);
          v2 = fmaxf(v2, 0.f); v3 = fmaxf(v3, 0.f);
        }
        u16x4 o = {f2bf(v0), f2bf(v1), f2bf(v2), f2bf(v3)};
        *(u16x4*)(SMEM + ml * 136 + nl) = o;
      }
    }
    __syncthreads();
    unsigned short* Cg = (unsigned short*)Cout;
    #pragma unroll
    for (int p = 0; p < 8; ++p) {
      int row = p * 16 + (tid >> 4);
      int col = (tid & 15) * 8;
      uint4 v = *(const uint4*)(SMEM + row * 136 + col);
      *(uint4*)(Cg + (m0 + row) * (long)N + n0 + col) = v;
    }
  }
}

// ---------------- NT i8 MFMA GEMM (16x16x64_i8, BK=64, LDS-staged C store) ----
__global__ __launch_bounds__(256) void gemm_nt_i8(
    const signed char* __restrict__ A,   // [M][K] i8
    const signed char* __restrict__ Bt,  // [N][K] i8
    const float* __restrict__ sa,        // [M]
    const float* __restrict__ sb,        // [N]
    const float* __restrict__ bias,      // [N]
    unsigned short* __restrict__ Cout,
    int K, int N, int gm, int gn, int relu) {
  __shared__ unsigned short SMEM[128 * 136];   // 34816 B (staging uses first 16KB)
  signed char* Asm = (signed char*)SMEM;       // 8192 B
  signed char* Bsm = Asm + 8192;               // 8192 B
  const int tid = threadIdx.x;
  const int w = tid >> 6;
  const int lane = tid & 63;
  const int wm = w & 1, wn = w >> 1;

  int b = blockIdx.x;
  int band = b / (gn * 8);
  int r = b - band * (gn * 8);
  int bm = gm - band * 8; if (bm > 8) bm = 8;
  const long m0 = ((long)band * 8 + (r % bm)) * 128;
  const long n0 = (long)(r / bm) * 128;

  const signed char* Ag = A + (m0 + 32 * w + (lane >> 2)) * (long)K + (lane & 3) * 16;
  const signed char* Bg = Bt + (n0 + 32 * w + (lane >> 2)) * (long)K + (lane & 3) * 16;
  signed char* AsmW = Asm + 32 * w * 64;
  signed char* BsmW = Bsm + 32 * w * 64;
  const long rstep = 16l * K;

  const int frow = lane & 15;
  const int fcol = (lane >> 4) * 16;

  i32x4 acc[4][4];
  i32x4 zero = {0, 0, 0, 0};
  #pragma unroll
  for (int i = 0; i < 4; ++i)
    #pragma unroll
    for (int j = 0; j < 4; ++j) acc[i][j] = zero;

  for (int kt = 0; kt < K; kt += 64) {
    __syncthreads();
    gload_lds16b(Ag + kt, AsmW);
    gload_lds16b(Ag + kt + rstep, AsmW + 16 * 64);
    gload_lds16b(Bg + kt, BsmW);
    gload_lds16b(Bg + kt + rstep, BsmW + 16 * 64);
    __syncthreads();
    i32x4 af[4], bfm[4];
    #pragma unroll
    for (int mt = 0; mt < 4; ++mt)
      af[mt] = *(const i32x4*)(Asm + (wm * 64 + mt * 16 + frow) * 64 + fcol);
    #pragma unroll
    for (int nt = 0; nt < 4; ++nt)
      bfm[nt] = *(const i32x4*)(Bsm + (wn * 64 + nt * 16 + frow) * 64 + fcol);
    #pragma unroll
    for (int mt = 0; mt < 4; ++mt)
      #pragma unroll
      for (int nt = 0; nt < 4; ++nt)
        acc[mt][nt] = __builtin_amdgcn_mfma_i32_16x16x64_i8(bfm[nt], af[mt], acc[mt][nt], 0, 0, 0);
  }

  const int nq = (lane >> 4) * 4;
  __syncthreads();   // staging LDS no longer needed; reuse as C tile
  #pragma unroll
  for (int mt = 0; mt < 4; ++mt) {
    int ml = wm * 64 + mt * 16 + frow;
    float sam = sa[m0 + ml];
    #pragma unroll
    for (int nt = 0; nt < 4; ++nt) {
      int nl = wn * 64 + nt * 16 + nq;
      float4 bv = *(const float4*)(bias + n0 + nl);
      float4 sbv = *(const float4*)(sb + n0 + nl);
      float v0 = (float)acc[mt][nt][0] * (sam * sbv.x) + bv.x;
      float v1 = (float)acc[mt][nt][1] * (sam * sbv.y) + bv.y;
      float v2 = (float)acc[mt][nt][2] * (sam * sbv.z) + bv.z;
      float v3 = (float)acc[mt][nt][3] * (sam * sbv.w) + bv.w;
      if (relu) {
        v0 = fmaxf(v0, 0.f); v1 = fmaxf(v1, 0.f);
        v2 = fmaxf(v2, 0.f); v3 = fmaxf(v3, 0.f);
      }
      u16x4 o = {f2bf(v0), f2bf(v1), f2bf(v2), f2bf(v3)};
      *(u16x4*)(SMEM + ml * 136 + nl) = o;
    }
  }
  __syncthreads();
  #pragma unroll
  for (int p = 0; p < 8; ++p) {
    int row = p * 16 + (tid >> 4);
    int col = (tid & 15) * 8;
    uint4 v = *(const uint4*)(SMEM + row * 136 + col);
    *(uint4*)(Cout + (m0 + row) * (long)N + n0 + col) = v;
  }
}

extern "C" void kernel_launch(void* const* d_in, const int* in_sizes, int n_in,
                              void* d_out, int out_size, void* d_ws, size_t ws_size,
                              hipStream_t stream) {
  (void)in_sizes; (void)n_in; (void)out_size; (void)ws_size;
  const int*   x          = (const int*)d_in[0];
  const int*   edge_index = (const int*)d_in[1];
  const int*   edge_attr  = (const int*)d_in[2];
  const int*   batch      = (const int*)d_in[3];
  const float* atom_emb1  = (const float*)d_in[4];
  const float* atom_emb2  = (const float*)d_in[5];
  const float* bond_emb1  = (const float*)d_in[6];   // [5][8][512]
  const float* bond_emb2  = (const float*)d_in[7];   // [5][4][512]
  const float* W1         = (const float*)d_in[8];   // [5][512][1024]
  const float* b1         = (const float*)d_in[9];   // [5][1024]
  const float* W2         = (const float*)d_in[10];  // [5][1024][512]
  const float* b2         = (const float*)d_in[11];  // [5][512]
  const float* pW1        = (const float*)d_in[12];  // [512][512]
  const float* pb1        = (const float*)d_in[13];
  const float* pW2        = (const float*)d_in[14];
  const float* pb2        = (const float*)d_in[15];

  // ---- workspace layout ----
  unsigned short* h      = (unsigned short*)d_ws;                 // MPAD*D bf16
  unsigned short* hidden = h + (size_t)MPAD * D;                  // MPAD*H2 bf16
  unsigned short* w2t    = hidden + (size_t)MPAD * H2;            // NL*D*H2 bf16
  unsigned short* pw1t   = w2t + (size_t)NL * D * H2;             // D*D
  unsigned short* pw2t   = pw1t + (size_t)D * D;                  // D*D
  unsigned short* pooled = pw2t + (size_t)D * D;                  // NG*D
  unsigned short* zmid   = pooled + (size_t)NG * D;               // NG*D
  signed char* aq  = (signed char*)(zmid + (size_t)NG * D);       // MPAD*512 i8
  signed char* w1q = aq + (size_t)MPAD * 512;                     // NL*H2*512 i8
  float* sa  = (float*)(w1q + (size_t)NL * H2 * 512);             // MPAD
  float* sw1 = sa + MPAD;                                         // NL*H2 (zero-init)
  int* indeg  = (int*)(sw1 + NL * H2);                            // NN+1 (zero-init)
  int* cur    = indeg + (NN + 1);                                 // NN   (zero-init)
  int* gcnt   = cur + NN;                                         // NG   (zero-init)
  int* offs   = gcnt + NG;                                        // NN+1
  int* goff   = offs + (NN + 1);                                  // NG+1
  int* packed = goff + (NG + 1);                                  // NE
  int* bsum   = packed + NE;                                      // 64

  // zero sw1 (absmax accum) + counters in one memset (adjacent)
  (void)hipMemsetAsync(sw1, 0, ((size_t)NL * H2 + (NN + 1) + NN + NG) * 4, stream);

  // W1 -> i8 [n][k] + per-col scales (split-K absmax, bit-pattern atomicMax)
  wmax_kernel<<<dim3(H2 / 256, NL, 16), 256, 0, stream>>>(W1, (unsigned*)sw1, D, H2);
  scale_kernel<<<(NL * H2 + 255) / 256, 256, 0, stream>>>((unsigned*)sw1, NL * H2);
  transpose_i8_kernel<<<dim3(H2 / 32, D / 32, NL), dim3(32, 8), 0, stream>>>(W1, w1q, sw1, D, H2);
  transpose_bf16_kernel<<<dim3(D / 32, H2 / 32, NL), dim3(32, 8), 0, stream>>>(W2, w2t, H2, D);
  transpose_bf16_kernel<<<dim3(D / 32, D / 32, 1), dim3(32, 8), 0, stream>>>(pW1, pw1t, D, D);
  transpose_bf16_kernel<<<dim3(D / 32, D / 32, 1), dim3(32, 8), 0, stream>>>(pW2, pw2t, D, D);

  atom_enc_kernel<<<(NN * 64) / 256, 256, 0, stream>>>(x, atom_emb1, atom_emb2, h);

  // CSR over dst (multi-block scan: 76us single-block scan was the #1 dispatch in R10)
  const int B1 = (NN + 4095) / 4096;   // 13
  count_kernel<<<(NE + 255) / 256, 256, 0, stream>>>(edge_index + NE, indeg, NE);
  scan_sums_kernel<<<B1, 1024, 0, stream>>>(indeg, bsum, NN);
  scan_partials_kernel<<<1, 64, 0, stream>>>(bsum, B1);
  scan_final_kernel<<<B1, 1024, 0, stream>>>(indeg, bsum, offs, NN);
  fill_csr_kernel<<<(NE + 255) / 256, 256, 0, stream>>>(edge_index, edge_attr, offs, cur, packed);

  // graph ranges (batch is sorted)
  const int B2 = (NG + 4095) / 4096;   // 1
  count_kernel<<<(NN + 255) / 256, 256, 0, stream>>>(batch, gcnt, NN);
  scan_sums_kernel<<<B2, 1024, 0, stream>>>(gcnt, bsum, NG);
  scan_partials_kernel<<<1, 64, 0, stream>>>(bsum, B2);
  scan_final_kernel<<<B2, 1024, 0, stream>>>(gcnt, bsum, goff, NG);

  const int GM = MPAD / 128;  // 391
  for (int l = 0; l < NL; ++l) {
    agg_kernel<<<(NN * 64) / 256, 256, 0, stream>>>(
        h, offs, packed, bond_emb1 + (size_t)l * 8 * D, bond_emb2 + (size_t)l * 4 * D, aq, sa);
    gemm_nt_i8<<<GM * (H2 / 128), 256, 0, stream>>>(
        aq, w1q + (size_t)l * H2 * 512, sa, sw1 + (size_t)l * H2, b1 + (size_t)l * H2,
        hidden, D, H2, GM, H2 / 128, 1);
    gemm_nt<<<GM * (D / 128), 256, 0, stream>>>(
        hidden, w2t + (size_t)l * D * H2, b2 + (size_t)l * D, h,
        H2, D, GM, D / 128, (l < NL - 1) ? 1 : 0, 0);
  }

  pool_kernel<<<(NG * 64) / 256, 256, 0, stream>>>(h, goff, pooled);
  gemm_nt<<<(NG / 128) * (D / 128), 256, 0, stream>>>(
      pooled, pw1t, pb1, zmid, D, D, NG / 128, D / 128, 1, 0);
  gemm_nt<<<(NG / 128) * (D / 128), 256, 0, stream>>>(
      zmid, pw2t, pb2, (float*)d_out, D, D, NG / 128, D / 128, 0, 1);
}

// Round 12
// 1111.533 us; speedup vs baseline: 1.2858x; 1.0769x over previous
//
#include <hip/hip_runtime.h>

#define NN 50000
#define NE 200000
#define NG 2048
#define D  512
#define H2 1024
#define NL 5
#define MPAD 50048   // 391 * 128

typedef __attribute__((ext_vector_type(8))) short bf16x8;
typedef __attribute__((ext_vector_type(4))) float f32x4;
typedef __attribute__((ext_vector_type(4))) int i32x4;
typedef __attribute__((ext_vector_type(4))) unsigned short u16x4;

__device__ __forceinline__ float bf2f(unsigned b) {
  union { unsigned u; float f; } c; c.u = b << 16; return c.f;
}
__device__ __forceinline__ unsigned short f2bf(float f) {
  union { float f; unsigned u; } c; c.f = f;
  return (unsigned short)((c.u + 0x7FFFu + ((c.u >> 16) & 1u)) >> 16);
}
__device__ __forceinline__ void add8(float* acc, uint4 v) {
  acc[0] += bf2f(v.x & 0xffffu); acc[1] += bf2f(v.x >> 16);
  acc[2] += bf2f(v.y & 0xffffu); acc[3] += bf2f(v.y >> 16);
  acc[4] += bf2f(v.z & 0xffffu); acc[5] += bf2f(v.z >> 16);
  acc[6] += bf2f(v.w & 0xffffu); acc[7] += bf2f(v.w >> 16);
}
__device__ __forceinline__ void addf8(float* acc, const float* p, float s) {
  float4 a = *(const float4*)p;
  float4 b = *(const float4*)(p + 4);
  acc[0] += s * a.x; acc[1] += s * a.y; acc[2] += s * a.z; acc[3] += s * a.w;
  acc[4] += s * b.x; acc[5] += s * b.y; acc[6] += s * b.z; acc[7] += s * b.w;
}
__device__ __forceinline__ uint4 pack8(const float* acc) {
  uint4 v;
  v.x = (unsigned)f2bf(acc[0]) | ((unsigned)f2bf(acc[1]) << 16);
  v.y = (unsigned)f2bf(acc[2]) | ((unsigned)f2bf(acc[3]) << 16);
  v.z = (unsigned)f2bf(acc[4]) | ((unsigned)f2bf(acc[5]) << 16);
  v.w = (unsigned)f2bf(acc[6]) | ((unsigned)f2bf(acc[7]) << 16);
  return v;
}
__device__ __forceinline__ void gload_lds16(const unsigned short* g, unsigned short* l) {
  __builtin_amdgcn_global_load_lds(
      (const __attribute__((address_space(1))) void*)g,
      (__attribute__((address_space(3))) void*)l, 16, 0, 0);
}
__device__ __forceinline__ void gload_lds16b(const signed char* g, signed char* l) {
  __builtin_amdgcn_global_load_lds(
      (const __attribute__((address_space(1))) void*)g,
      (__attribute__((address_space(3))) void*)l, 16, 0, 0);
}
__device__ __forceinline__ int q8(float v, float inv) {
  int q = (int)rintf(v * inv);
  if (q > 127) q = 127;
  if (q < -127) q = -127;
  return q;
}

// ---------------- atom encoder: h[n] = ae1[x0] + ae2[x1]  (bf16 out) ----------
__global__ void atom_enc_kernel(const int* __restrict__ x,
                                const float* __restrict__ ae1,
                                const float* __restrict__ ae2,
                                unsigned short* __restrict__ h) {
  int gid = blockIdx.x * 256 + threadIdx.x;
  int n = gid >> 6;
  if (n >= NN) return;
  int d0 = (gid & 63) << 3;
  int x0 = x[2 * n], x1 = x[2 * n + 1];
  float acc[8] = {0, 0, 0, 0, 0, 0, 0, 0};
  addf8(acc, ae1 + (size_t)x0 * D + d0, 1.0f);
  addf8(acc, ae2 + (size_t)x1 * D + d0, 1.0f);
  *(uint4*)(h + (size_t)n * D + d0) = pack8(acc);
}

// ---------------- CSR build ---------------------------------------------------
__global__ void count_kernel(const int* __restrict__ keys, int* __restrict__ cnt, int n) {
  int i = blockIdx.x * 256 + threadIdx.x;
  if (i < n) atomicAdd(&cnt[keys[i]], 1);
}

// ---- 3-phase multi-block exclusive scan (4096 elems/block, int4-coalesced) ---
__global__ void scan_sums_kernel(const int* __restrict__ in, int* __restrict__ bsum, int n) {
  __shared__ int sm[1024];
  int t = threadIdx.x;
  int base = blockIdx.x * 4096 + t * 4;
  int s = 0;
  if (base + 3 < n) {
    int4 v = *(const int4*)(in + base);
    s = v.x + v.y + v.z + v.w;
  } else {
    for (int i = 0; i < 4; ++i) if (base + i < n) s += in[base + i];
  }
  sm[t] = s;
  __syncthreads();
  for (int d = 512; d > 0; d >>= 1) {
    if (t < d) sm[t] += sm[t + d];
    __syncthreads();
  }
  if (t == 0) bsum[blockIdx.x] = sm[0];
}

__global__ void scan_partials_kernel(int* __restrict__ bsum, int B) {
  if (threadIdx.x == 0 && blockIdx.x == 0) {
    int run = 0;
    for (int i = 0; i < B; ++i) { int v = bsum[i]; bsum[i] = run; run += v; }
    bsum[B] = run;
  }
}

__global__ void scan_final_kernel(const int* __restrict__ in, const int* __restrict__ bsum,
                                  int* __restrict__ out, int n) {
  __shared__ int sm[2][1024];
  int t = threadIdx.x;
  int base = blockIdx.x * 4096 + t * 4;
  int v0 = 0, v1 = 0, v2 = 0, v3 = 0;
  if (base + 3 < n) {
    int4 v = *(const int4*)(in + base);
    v0 = v.x; v1 = v.y; v2 = v.z; v3 = v.w;
  } else {
    if (base + 0 < n) v0 = in[base + 0];
    if (base + 1 < n) v1 = in[base + 1];
    if (base + 2 < n) v2 = in[base + 2];
    if (base + 3 < n) v3 = in[base + 3];
  }
  int local = v0 + v1 + v2 + v3;
  sm[0][t] = local;
  __syncthreads();
  int pi = 0;
  for (int dd = 1; dd < 1024; dd <<= 1) {
    int v = sm[pi][t];
    if (t >= dd) v += sm[pi][t - dd];
    sm[pi ^ 1][t] = v;
    pi ^= 1;
    __syncthreads();
  }
  int pre = sm[pi][t] - local + bsum[blockIdx.x];
  if (base + 3 < n) {
    int4 o; o.x = pre; o.y = pre + v0; o.z = pre + v0 + v1; o.w = pre + v0 + v1 + v2;
    *(int4*)(out + base) = o;
  } else {
    if (base + 0 < n) out[base + 0] = pre;
    if (base + 1 < n) out[base + 1] = pre + v0;
    if (base + 2 < n) out[base + 2] = pre + v0 + v1;
    if (base + 3 < n) out[base + 3] = pre + v0 + v1 + v2;
  }
  if (blockIdx.x == 0 && t == 0) out[n] = bsum[gridDim.x];
}

__global__ void fill_csr_kernel(const int* __restrict__ ei, const int* __restrict__ ea,
                                const int* __restrict__ offs, int* __restrict__ cur,
                                int* __restrict__ packed) {
  int e = blockIdx.x * 256 + threadIdx.x;
  if (e >= NE) return;
  int dst = ei[NE + e];
  int pos = offs[dst] + atomicAdd(&cur[dst], 1);
  packed[pos] = (ei[e] & 0x1FFFF) | ((ea[2 * e] & 3) << 17) | ((ea[2 * e + 1] & 3) << 20);
}

// ---------------- aggregation + dynamic per-row i8 quantization ---------------
__global__ void agg_kernel(const unsigned short* __restrict__ h,
                           const int* __restrict__ offs,
                           const int* __restrict__ packed,
                           const float* __restrict__ be1,   // [8][512] layer slice
                           const float* __restrict__ be2,   // [4][512] layer slice
                           signed char* __restrict__ aq,    // [MPAD][512] i8
                           float* __restrict__ sa) {        // [MPAD] row scales
  int gid = blockIdx.x * 256 + threadIdx.x;
  int n = gid >> 6;
  if (n >= NN) return;
  int d0 = (gid & 63) << 3;
  float acc[8] = {0, 0, 0, 0, 0, 0, 0, 0};
  add8(acc, *(const uint4*)(h + (size_t)n * D + d0));
  addf8(acc, be1 + 6 * D + d0, 1.0f);
  addf8(acc, be2 + 3 * D + d0, 1.0f);
  int beg = offs[n], end = offs[n + 1];
  unsigned c0 = 0, c1 = 0;
  int i = beg;
  for (; i + 4 <= end; i += 4) {
    int p0 = packed[i], p1 = packed[i + 1], p2 = packed[i + 2], p3 = packed[i + 3];
    uint4 v0 = *(const uint4*)(h + (size_t)(p0 & 0x1FFFF) * D + d0);
    uint4 v1 = *(const uint4*)(h + (size_t)(p1 & 0x1FFFF) * D + d0);
    uint4 v2 = *(const uint4*)(h + (size_t)(p2 & 0x1FFFF) * D + d0);
    uint4 v3 = *(const uint4*)(h + (size_t)(p3 & 0x1FFFF) * D + d0);
    c0 += (1u << (((p0 >> 17) & 3) * 8)) + (1u << (((p1 >> 17) & 3) * 8)) +
          (1u << (((p2 >> 17) & 3) * 8)) + (1u << (((p3 >> 17) & 3) * 8));
    c1 += (1u << (((p0 >> 20) & 3) * 8)) + (1u << (((p1 >> 20) & 3) * 8)) +
          (1u << (((p2 >> 20) & 3) * 8)) + (1u << (((p3 >> 20) & 3) * 8));
    add8(acc, v0); add8(acc, v1); add8(acc, v2); add8(acc, v3);
  }
  for (; i < end; ++i) {
    int p = packed[i];
    c0 += 1u << (((p >> 17) & 3) * 8);
    c1 += 1u << (((p >> 20) & 3) * 8);
    add8(acc, *(const uint4*)(h + (size_t)(p & 0x1FFFF) * D + d0));
  }
  #pragma unroll
  for (int v = 0; v < 3; ++v) {
    float s0 = (float)((c0 >> (8 * v)) & 0xffu);
    float s1 = (float)((c1 >> (8 * v)) & 0xffu);
    if (s0 != 0.f) addf8(acc, be1 + v * D + d0, s0);
    if (s1 != 0.f) addf8(acc, be2 + v * D + d0, s1);
  }
  float mx = 0.f;
  #pragma unroll
  for (int j = 0; j < 8; ++j) mx = fmaxf(mx, fabsf(acc[j]));
  #pragma unroll
  for (int o = 32; o > 0; o >>= 1) mx = fmaxf(mx, __shfl_xor(mx, o));
  float s = mx * (1.0f / 127.0f);
  if (s < 1e-30f) s = 1e-30f;
  float inv = 1.0f / s;
  int q[8];
  #pragma unroll
  for (int j = 0; j < 8; ++j) q[j] = q8(acc[j], inv);
  uint2 pk;
  pk.x = (q[0] & 0xff) | ((q[1] & 0xff) << 8) | ((q[2] & 0xff) << 16) | ((q[3] & 0xff) << 24);
  pk.y = (q[4] & 0xff) | ((q[5] & 0xff) << 8) | ((q[6] & 0xff) << 16) | ((q[7] & 0xff) << 24);
  *(uint2*)(aq + (size_t)n * 512 + d0) = pk;
  if ((gid & 63) == 0) sa[n] = s;
}

// ---------------- mean pooling: one wave per graph ----------------------------
__global__ void pool_kernel(const unsigned short* __restrict__ h,
                            const int* __restrict__ goff,
                            unsigned short* __restrict__ pooled) {
  int gid = blockIdx.x * 256 + threadIdx.x;
  int g = gid >> 6;
  if (g >= NG) return;
  int d0 = (gid & 63) << 3;
  int beg = goff[g], end = goff[g + 1];
  float acc[8] = {0, 0, 0, 0, 0, 0, 0, 0};
  for (int nd = beg; nd < end; ++nd)
    add8(acc, *(const uint4*)(h + (size_t)nd * D + d0));
  int c = end - beg; if (c < 1) c = 1;
  float inv = 1.0f / (float)c;
  #pragma unroll
  for (int j = 0; j < 8; ++j) acc[j] *= inv;
  *(uint4*)(pooled + (size_t)g * D + d0) = pack8(acc);
}

// ---------------- f32 [R][C] -> bf16 [C][R] transpose (weights) ---------------
__global__ void transpose_bf16_kernel(const float* __restrict__ in,
                                      unsigned short* __restrict__ out,
                                      int R, int C) {
  __shared__ float tile[32][33];
  const float* inp = in + (size_t)blockIdx.z * R * C;
  unsigned short* outp = out + (size_t)blockIdx.z * R * C;
  int c0 = blockIdx.x * 32, r0 = blockIdx.y * 32;
  int tx = threadIdx.x, ty = threadIdx.y;  // (32, 8)
  #pragma unroll
  for (int j = 0; j < 32; j += 8)
    tile[ty + j][tx] = inp[(size_t)(r0 + ty + j) * C + (c0 + tx)];
  __syncthreads();
  #pragma unroll
  for (int j = 0; j < 32; j += 8)
    outp[(size_t)(c0 + ty + j) * R + (r0 + tx)] = f2bf(tile[tx][ty + j]);
}

// ---------------- W1 per-output-column absmax, split-K + atomicMax on bits ----
__global__ void wmax_kernel(const float* __restrict__ W, unsigned* __restrict__ swbits,
                            int K, int N) {
  int n = blockIdx.x * 256 + threadIdx.x;
  const float* Wl = W + (size_t)blockIdx.y * K * N;
  int kper = K / gridDim.z;
  int k0 = blockIdx.z * kper;
  float mx = 0.f;
  for (int k = k0; k < k0 + kper; ++k)
    mx = fmaxf(mx, fabsf(Wl[(size_t)k * N + n]));
  atomicMax(&swbits[(size_t)blockIdx.y * N + n], __float_as_uint(mx));
}

__global__ void scale_kernel(unsigned* __restrict__ swbits, int n) {
  int i = blockIdx.x * 256 + threadIdx.x;
  if (i >= n) return;
  float mx = __uint_as_float(swbits[i]);
  float s = mx * (1.0f / 127.0f);
  if (s < 1e-30f) s = 1e-30f;
  ((float*)swbits)[i] = s;
}

// ---------------- f32 [R][C] -> i8 [C][R] transpose + quant -------------------
__global__ void transpose_i8_kernel(const float* __restrict__ in,
                                    signed char* __restrict__ out,
                                    const float* __restrict__ sw,
                                    int R, int C) {
  __shared__ float tile[32][33];
  const float* inp = in + (size_t)blockIdx.z * R * C;
  signed char* outp = out + (size_t)blockIdx.z * R * C;
  const float* swp = sw + (size_t)blockIdx.z * C;
  int c0 = blockIdx.x * 32, r0 = blockIdx.y * 32;
  int tx = threadIdx.x, ty = threadIdx.y;  // (32, 8)
  #pragma unroll
  for (int j = 0; j < 32; j += 8)
    tile[ty + j][tx] = inp[(size_t)(r0 + ty + j) * C + (c0 + tx)];
  __syncthreads();
  #pragma unroll
  for (int j = 0; j < 32; j += 8) {
    int oc = c0 + ty + j;
    float inv = 1.0f / swp[oc];
    outp[(size_t)oc * R + (r0 + tx)] = (signed char)q8(tile[tx][ty + j], inv);
  }
}

// ---------------- NT bf16 MFMA GEMM (R6 K-loop + R9 LDS-staged C store) -------
// __launch_bounds__(256, 4): cap regs for 4 waves/SIMD (R11: 84 VGPR + 64 AGPR
// = 148 -> 3 waves/SIMD; LDS allows 4 blocks/CU). More resident blocks amortize
// each block's barrier vmcnt-drain (m114 implicit overlap).
__global__ __launch_bounds__(256, 4) void gemm_nt(
    const unsigned short* __restrict__ A,
    const unsigned short* __restrict__ Bt,
    const float* __restrict__ bias,
    void* __restrict__ Cout,
    int K, int N, int gm, int gn, int relu, int out_f32) {
  __shared__ unsigned short SMEM[128 * 136];   // 34816 B
  unsigned short* Asm = SMEM;                  // 4096 elems
  unsigned short* Bsm = SMEM + 4096;           // 4096 elems
  const int tid = threadIdx.x;
  const int w = tid >> 6;
  const int lane = tid & 63;
  const int wm = w & 1, wn = w >> 1;

  int b = blockIdx.x;
  int band = b / (gn * 8);
  int r = b - band * (gn * 8);
  int bm = gm - band * 8; if (bm > 8) bm = 8;
  const long m0 = ((long)band * 8 + (r % bm)) * 128;
  const long n0 = (long)(r / bm) * 128;

  const unsigned short* Ag = A + (m0 + 32 * w + (lane >> 2)) * (long)K + (lane & 3) * 8;
  const unsigned short* Bg = Bt + (n0 + 32 * w + (lane >> 2)) * (long)K + (lane & 3) * 8;
  unsigned short* AsmW = Asm + 32 * w * 32;
  unsigned short* BsmW = Bsm + 32 * w * 32;
  const long rstep = 16l * K;

  const int frow = lane & 15;
  const int fcol = (lane >> 4) * 8;

  f32x4 acc[4][4];
  f32x4 zero = {0.f, 0.f, 0.f, 0.f};
  #pragma unroll
  for (int i = 0; i < 4; ++i)
    #pragma unroll
    for (int j = 0; j < 4; ++j) acc[i][j] = zero;

  for (int kt = 0; kt < K; kt += 32) {
    __syncthreads();
    gload_lds16(Ag + kt, AsmW);
    gload_lds16(Ag + kt + rstep, AsmW + 16 * 32);
    gload_lds16(Bg + kt, BsmW);
    gload_lds16(Bg + kt + rstep, BsmW + 16 * 32);
    __syncthreads();
    bf16x8 af[4], bfm[4];
    #pragma unroll
    for (int mt = 0; mt < 4; ++mt)
      af[mt] = *(const bf16x8*)(Asm + (wm * 64 + mt * 16 + frow) * 32 + fcol);
    #pragma unroll
    for (int nt = 0; nt < 4; ++nt)
      bfm[nt] = *(const bf16x8*)(Bsm + (wn * 64 + nt * 16 + frow) * 32 + fcol);
    #pragma unroll
    for (int mt = 0; mt < 4; ++mt)
      #pragma unroll
      for (int nt = 0; nt < 4; ++nt)
        acc[mt][nt] = __builtin_amdgcn_mfma_f32_16x16x32_bf16(bfm[nt], af[mt], acc[mt][nt], 0, 0, 0);
  }

  const int nq = (lane >> 4) * 4;
  if (out_f32) {
    #pragma unroll
    for (int mt = 0; mt < 4; ++mt) {
      long gm_ = m0 + wm * 64 + mt * 16 + frow;
      #pragma unroll
      for (int nt = 0; nt < 4; ++nt) {
        long gn_ = n0 + wn * 64 + nt * 16 + nq;
        float4 bv = *(const float4*)(bias + gn_);
        float v0 = acc[mt][nt][0] + bv.x;
        float v1 = acc[mt][nt][1] + bv.y;
        float v2 = acc[mt][nt][2] + bv.z;
        float v3 = acc[mt][nt][3] + bv.w;
        if (relu) {
          v0 = fmaxf(v0, 0.f); v1 = fmaxf(v1, 0.f);
          v2 = fmaxf(v2, 0.f); v3 = fmaxf(v3, 0.f);
        }
        float4 o = {v0, v1, v2, v3};
        *(float4*)((float*)Cout + gm_ * (long)N + gn_) = o;
      }
    }
  } else {
    __syncthreads();   // staging LDS no longer needed; reuse as C tile
    #pragma unroll
    for (int mt = 0; mt < 4; ++mt) {
      int ml = wm * 64 + mt * 16 + frow;
      #pragma unroll
      for (int nt = 0; nt < 4; ++nt) {
        int nl = wn * 64 + nt * 16 + nq;
        float4 bv = *(const float4*)(bias + n0 + nl);
        float v0 = acc[mt][nt][0] + bv.x;
        float v1 = acc[mt][nt][1] + bv.y;
        float v2 = acc[mt][nt][2] + bv.z;
        float v3 = acc[mt][nt][3] + bv.w;
        if (relu) {
          v0 = fmaxf(v0, 0.f); v1 = fmaxf(v1, 0.f);
          v2 = fmaxf(v2, 0.f); v3 = fmaxf(v3, 0.f);
        }
        u16x4 o = {f2bf(v0), f2bf(v1), f2bf(v2), f2bf(v3)};
        *(u16x4*)(SMEM + ml * 136 + nl) = o;
      }
    }
    __syncthreads();
    unsigned short* Cg = (unsigned short*)Cout;
    #pragma unroll
    for (int p = 0; p < 8; ++p) {
      int row = p * 16 + (tid >> 4);
      int col = (tid & 15) * 8;
      uint4 v = *(const uint4*)(SMEM + row * 136 + col);
      *(uint4*)(Cg + (m0 + row) * (long)N + n0 + col) = v;
    }
  }
}

// ---------------- NT i8 MFMA GEMM (16x16x64_i8, BK=64, LDS-staged C store) ----
__global__ __launch_bounds__(256) void gemm_nt_i8(
    const signed char* __restrict__ A,   // [M][K] i8
    const signed char* __restrict__ Bt,  // [N][K] i8
    const float* __restrict__ sa,        // [M]
    const float* __restrict__ sb,        // [N]
    const float* __restrict__ bias,      // [N]
    unsigned short* __restrict__ Cout,
    int K, int N, int gm, int gn, int relu) {
  __shared__ unsigned short SMEM[128 * 136];   // 34816 B (staging uses first 16KB)
  signed char* Asm = (signed char*)SMEM;       // 8192 B
  signed char* Bsm = Asm + 8192;               // 8192 B
  const int tid = threadIdx.x;
  const int w = tid >> 6;
  const int lane = tid & 63;
  const int wm = w & 1, wn = w >> 1;

  int b = blockIdx.x;
  int band = b / (gn * 8);
  int r = b - band * (gn * 8);
  int bm = gm - band * 8; if (bm > 8) bm = 8;
  const long m0 = ((long)band * 8 + (r % bm)) * 128;
  const long n0 = (long)(r / bm) * 128;

  const signed char* Ag = A + (m0 + 32 * w + (lane >> 2)) * (long)K + (lane & 3) * 16;
  const signed char* Bg = Bt + (n0 + 32 * w + (lane >> 2)) * (long)K + (lane & 3) * 16;
  signed char* AsmW = Asm + 32 * w * 64;
  signed char* BsmW = Bsm + 32 * w * 64;
  const long rstep = 16l * K;

  const int frow = lane & 15;
  const int fcol = (lane >> 4) * 16;

  i32x4 acc[4][4];
  i32x4 zero = {0, 0, 0, 0};
  #pragma unroll
  for (int i = 0; i < 4; ++i)
    #pragma unroll
    for (int j = 0; j < 4; ++j) acc[i][j] = zero;

  for (int kt = 0; kt < K; kt += 64) {
    __syncthreads();
    gload_lds16b(Ag + kt, AsmW);
    gload_lds16b(Ag + kt + rstep, AsmW + 16 * 64);
    gload_lds16b(Bg + kt, BsmW);
    gload_lds16b(Bg + kt + rstep, BsmW + 16 * 64);
    __syncthreads();
    i32x4 af[4], bfm[4];
    #pragma unroll
    for (int mt = 0; mt < 4; ++mt)
      af[mt] = *(const i32x4*)(Asm + (wm * 64 + mt * 16 + frow) * 64 + fcol);
    #pragma unroll
    for (int nt = 0; nt < 4; ++nt)
      bfm[nt] = *(const i32x4*)(Bsm + (wn * 64 + nt * 16 + frow) * 64 + fcol);
    #pragma unroll
    for (int mt = 0; mt < 4; ++mt)
      #pragma unroll
      for (int nt = 0; nt < 4; ++nt)
        acc[mt][nt] = __builtin_amdgcn_mfma_i32_16x16x64_i8(bfm[nt], af[mt], acc[mt][nt], 0, 0, 0);
  }

  const int nq = (lane >> 4) * 4;
  __syncthreads();   // staging LDS no longer needed; reuse as C tile
  #pragma unroll
  for (int mt = 0; mt < 4; ++mt) {
    int ml = wm * 64 + mt * 16 + frow;
    float sam = sa[m0 + ml];
    #pragma unroll
    for (int nt = 0; nt < 4; ++nt) {
      int nl = wn * 64 + nt * 16 + nq;
      float4 bv = *(const float4*)(bias + n0 + nl);
      float4 sbv = *(const float4*)(sb + n0 + nl);
      float v0 = (float)acc[mt][nt][0] * (sam * sbv.x) + bv.x;
      float v1 = (float)acc[mt][nt][1] * (sam * sbv.y) + bv.y;
      float v2 = (float)acc[mt][nt][2] * (sam * sbv.z) + bv.z;
      float v3 = (float)acc[mt][nt][3] * (sam * sbv.w) + bv.w;
      if (relu) {
        v0 = fmaxf(v0, 0.f); v1 = fmaxf(v1, 0.f);
        v2 = fmaxf(v2, 0.f); v3 = fmaxf(v3, 0.f);
      }
      u16x4 o = {f2bf(v0), f2bf(v1), f2bf(v2), f2bf(v3)};
      *(u16x4*)(SMEM + ml * 136 + nl) = o;
    }
  }
  __syncthreads();
  #pragma unroll
  for (int p = 0; p < 8; ++p) {
    int row = p * 16 + (tid >> 4);
    int col = (tid & 15) * 8;
    uint4 v = *(const uint4*)(SMEM + row * 136 + col);
    *(uint4*)(Cout + (m0 + row) * (long)N + n0 + col) = v;
  }
}

extern "C" void kernel_launch(void* const* d_in, const int* in_sizes, int n_in,
                              void* d_out, int out_size, void* d_ws, size_t ws_size,
                              hipStream_t stream) {
  (void)in_sizes; (void)n_in; (void)out_size; (void)ws_size;
  const int*   x          = (const int*)d_in[0];
  const int*   edge_index = (const int*)d_in[1];
  const int*   edge_attr  = (const int*)d_in[2];
  const int*   batch      = (const int*)d_in[3];
  const float* atom_emb1  = (const float*)d_in[4];
  const float* atom_emb2  = (const float*)d_in[5];
  const float* bond_emb1  = (const float*)d_in[6];   // [5][8][512]
  const float* bond_emb2  = (const float*)d_in[7];   // [5][4][512]
  const float* W1         = (const float*)d_in[8];   // [5][512][1024]
  const float* b1         = (const float*)d_in[9];   // [5][1024]
  const float* W2         = (const float*)d_in[10];  // [5][1024][512]
  const float* b2         = (const float*)d_in[11];  // [5][512]
  const float* pW1        = (const float*)d_in[12];  // [512][512]
  const float* pb1        = (const float*)d_in[13];
  const float* pW2        = (const float*)d_in[14];
  const float* pb2        = (const float*)d_in[15];

  // ---- workspace layout ----
  unsigned short* h      = (unsigned short*)d_ws;                 // MPAD*D bf16
  unsigned short* hidden = h + (size_t)MPAD * D;                  // MPAD*H2 bf16
  unsigned short* w2t    = hidden + (size_t)MPAD * H2;            // NL*D*H2 bf16
  unsigned short* pw1t   = w2t + (size_t)NL * D * H2;             // D*D
  unsigned short* pw2t   = pw1t + (size_t)D * D;                  // D*D
  unsigned short* pooled = pw2t + (size_t)D * D;                  // NG*D
  unsigned short* zmid   = pooled + (size_t)NG * D;               // NG*D
  signed char* aq  = (signed char*)(zmid + (size_t)NG * D);       // MPAD*512 i8
  signed char* w1q = aq + (size_t)MPAD * 512;                     // NL*H2*512 i8
  float* sa  = (float*)(w1q + (size_t)NL * H2 * 512);             // MPAD
  float* sw1 = sa + MPAD;                                         // NL*H2 (zero-init)
  int* indeg  = (int*)(sw1 + NL * H2);                            // NN+1 (zero-init)
  int* cur    = indeg + (NN + 1);                                 // NN   (zero-init)
  int* gcnt   = cur + NN;                                         // NG   (zero-init)
  int* offs   = gcnt + NG;                                        // NN+1
  int* goff   = offs + (NN + 1);                                  // NG+1
  int* packed = goff + (NG + 1);                                  // NE
  int* bsum   = packed + NE;                                      // 64

  // zero sw1 (absmax accum) + counters in one memset (adjacent)
  (void)hipMemsetAsync(sw1, 0, ((size_t)NL * H2 + (NN + 1) + NN + NG) * 4, stream);

  // W1 -> i8 [n][k] + per-col scales (split-K absmax, bit-pattern atomicMax)
  wmax_kernel<<<dim3(H2 / 256, NL, 16), 256, 0, stream>>>(W1, (unsigned*)sw1, D, H2);
  scale_kernel<<<(NL * H2 + 255) / 256, 256, 0, stream>>>((unsigned*)sw1, NL * H2);
  transpose_i8_kernel<<<dim3(H2 / 32, D / 32, NL), dim3(32, 8), 0, stream>>>(W1, w1q, sw1, D, H2);
  transpose_bf16_kernel<<<dim3(D / 32, H2 / 32, NL), dim3(32, 8), 0, stream>>>(W2, w2t, H2, D);
  transpose_bf16_kernel<<<dim3(D / 32, D / 32, 1), dim3(32, 8), 0, stream>>>(pW1, pw1t, D, D);
  transpose_bf16_kernel<<<dim3(D / 32, D / 32, 1), dim3(32, 8), 0, stream>>>(pW2, pw2t, D, D);

  atom_enc_kernel<<<(NN * 64) / 256, 256, 0, stream>>>(x, atom_emb1, atom_emb2, h);

  // CSR over dst (multi-block scan)
  const int B1 = (NN + 4095) / 4096;   // 13
  count_kernel<<<(NE + 255) / 256, 256, 0, stream>>>(edge_index + NE, indeg, NE);
  scan_sums_kernel<<<B1, 1024, 0, stream>>>(indeg, bsum, NN);
  scan_partials_kernel<<<1, 64, 0, stream>>>(bsum, B1);
  scan_final_kernel<<<B1, 1024, 0, stream>>>(indeg, bsum, offs, NN);
  fill_csr_kernel<<<(NE + 255) / 256, 256, 0, stream>>>(edge_index, edge_attr, offs, cur, packed);

  // graph ranges (batch is sorted)
  const int B2 = (NG + 4095) / 4096;   // 1
  count_kernel<<<(NN + 255) / 256, 256, 0, stream>>>(batch, gcnt, NN);
  scan_sums_kernel<<<B2, 1024, 0, stream>>>(gcnt, bsum, NG);
  scan_partials_kernel<<<1, 64, 0, stream>>>(bsum, B2);
  scan_final_kernel<<<B2, 1024, 0, stream>>>(gcnt, bsum, goff, NG);

  const int GM = MPAD / 128;  // 391
  for (int l = 0; l < NL; ++l) {
    agg_kernel<<<(NN * 64) / 256, 256, 0, stream>>>(
        h, offs, packed, bond_emb1 + (size_t)l * 8 * D, bond_emb2 + (size_t)l * 4 * D, aq, sa);
    gemm_nt_i8<<<GM * (H2 / 128), 256, 0, stream>>>(
        aq, w1q + (size_t)l * H2 * 512, sa, sw1 + (size_t)l * H2, b1 + (size_t)l * H2,
        hidden, D, H2, GM, H2 / 128, 1);
    gemm_nt<<<GM * (D / 128), 256, 0, stream>>>(
        hidden, w2t + (size_t)l * D * H2, b2 + (size_t)l * D, h,
        H2, D, GM, D / 128, (l < NL - 1) ? 1 : 0, 0);
  }

  pool_kernel<<<(NG * 64) / 256, 256, 0, stream>>>(h, goff, pooled);
  gemm_nt<<<(NG / 128) * (D / 128), 256, 0, stream>>>(
      pooled, pw1t, pb1, zmid, D, D, NG / 128, D / 128, 1, 0);
  gemm_nt<<<(NG / 128) * (D / 128), 256, 0, stream>>>(
      zmid, pw2t, pb2, (float*)d_out, D, D, NG / 128, D / 128, 0, 1);
}

// Round 13
// 989.305 us; speedup vs baseline: 1.4447x; 1.1235x over previous
//
#include <hip/hip_runtime.h>

#define NN 50000
#define NE 200000
#define NG 2048
#define D  512
#define H2 1024
#define NL 5
#define MPAD 50048   // 391 * 128

typedef __attribute__((ext_vector_type(8))) short bf16x8;
typedef __attribute__((ext_vector_type(4))) float f32x4;
typedef __attribute__((ext_vector_type(4))) int i32x4;
typedef __attribute__((ext_vector_type(4))) unsigned short u16x4;

__device__ __forceinline__ float bf2f(unsigned b) {
  union { unsigned u; float f; } c; c.u = b << 16; return c.f;
}
__device__ __forceinline__ unsigned short f2bf(float f) {
  union { float f; unsigned u; } c; c.f = f;
  return (unsigned short)((c.u + 0x7FFFu + ((c.u >> 16) & 1u)) >> 16);
}
__device__ __forceinline__ void add8(float* acc, uint4 v) {
  acc[0] += bf2f(v.x & 0xffffu); acc[1] += bf2f(v.x >> 16);
  acc[2] += bf2f(v.y & 0xffffu); acc[3] += bf2f(v.y >> 16);
  acc[4] += bf2f(v.z & 0xffffu); acc[5] += bf2f(v.z >> 16);
  acc[6] += bf2f(v.w & 0xffffu); acc[7] += bf2f(v.w >> 16);
}
__device__ __forceinline__ void addf8(float* acc, const float* p, float s) {
  float4 a = *(const float4*)p;
  float4 b = *(const float4*)(p + 4);
  acc[0] += s * a.x; acc[1] += s * a.y; acc[2] += s * a.z; acc[3] += s * a.w;
  acc[4] += s * b.x; acc[5] += s * b.y; acc[6] += s * b.z; acc[7] += s * b.w;
}
__device__ __forceinline__ uint4 pack8(const float* acc) {
  uint4 v;
  v.x = (unsigned)f2bf(acc[0]) | ((unsigned)f2bf(acc[1]) << 16);
  v.y = (unsigned)f2bf(acc[2]) | ((unsigned)f2bf(acc[3]) << 16);
  v.z = (unsigned)f2bf(acc[4]) | ((unsigned)f2bf(acc[5]) << 16);
  v.w = (unsigned)f2bf(acc[6]) | ((unsigned)f2bf(acc[7]) << 16);
  return v;
}
__device__ __forceinline__ void gload_lds16(const unsigned short* g, unsigned short* l) {
  __builtin_amdgcn_global_load_lds(
      (const __attribute__((address_space(1))) void*)g,
      (__attribute__((address_space(3))) void*)l, 16, 0, 0);
}
__device__ __forceinline__ void gload_lds16b(const signed char* g, signed char* l) {
  __builtin_amdgcn_global_load_lds(
      (const __attribute__((address_space(1))) void*)g,
      (__attribute__((address_space(3))) void*)l, 16, 0, 0);
}
__device__ __forceinline__ int q8(float v, float inv) {
  int q = (int)rintf(v * inv);
  if (q > 127) q = 127;
  if (q < -127) q = -127;
  return q;
}

// ---------------- atom encoder: h[n] = ae1[x0] + ae2[x1]  (bf16 out) ----------
__global__ void atom_enc_kernel(const int* __restrict__ x,
                                const float* __restrict__ ae1,
                                const float* __restrict__ ae2,
                                unsigned short* __restrict__ h) {
  int gid = blockIdx.x * 256 + threadIdx.x;
  int n = gid >> 6;
  if (n >= NN) return;
  int d0 = (gid & 63) << 3;
  int x0 = x[2 * n], x1 = x[2 * n + 1];
  float acc[8] = {0, 0, 0, 0, 0, 0, 0, 0};
  addf8(acc, ae1 + (size_t)x0 * D + d0, 1.0f);
  addf8(acc, ae2 + (size_t)x1 * D + d0, 1.0f);
  *(uint4*)(h + (size_t)n * D + d0) = pack8(acc);
}

// ---------------- CSR build ---------------------------------------------------
__global__ void count_kernel(const int* __restrict__ keys, int* __restrict__ cnt, int n) {
  int i = blockIdx.x * 256 + threadIdx.x;
  if (i < n) atomicAdd(&cnt[keys[i]], 1);
}

// ---- 3-phase multi-block exclusive scan (4096 elems/block, int4-coalesced) ---
__global__ void scan_sums_kernel(const int* __restrict__ in, int* __restrict__ bsum, int n) {
  __shared__ int sm[1024];
  int t = threadIdx.x;
  int base = blockIdx.x * 4096 + t * 4;
  int s = 0;
  if (base + 3 < n) {
    int4 v = *(const int4*)(in + base);
    s = v.x + v.y + v.z + v.w;
  } else {
    for (int i = 0; i < 4; ++i) if (base + i < n) s += in[base + i];
  }
  sm[t] = s;
  __syncthreads();
  for (int d = 512; d > 0; d >>= 1) {
    if (t < d) sm[t] += sm[t + d];
    __syncthreads();
  }
  if (t == 0) bsum[blockIdx.x] = sm[0];
}

__global__ void scan_partials_kernel(int* __restrict__ bsum, int B) {
  if (threadIdx.x == 0 && blockIdx.x == 0) {
    int run = 0;
    for (int i = 0; i < B; ++i) { int v = bsum[i]; bsum[i] = run; run += v; }
    bsum[B] = run;
  }
}

__global__ void scan_final_kernel(const int* __restrict__ in, const int* __restrict__ bsum,
                                  int* __restrict__ out, int n) {
  __shared__ int sm[2][1024];
  int t = threadIdx.x;
  int base = blockIdx.x * 4096 + t * 4;
  int v0 = 0, v1 = 0, v2 = 0, v3 = 0;
  if (base + 3 < n) {
    int4 v = *(const int4*)(in + base);
    v0 = v.x; v1 = v.y; v2 = v.z; v3 = v.w;
  } else {
    if (base + 0 < n) v0 = in[base + 0];
    if (base + 1 < n) v1 = in[base + 1];
    if (base + 2 < n) v2 = in[base + 2];
    if (base + 3 < n) v3 = in[base + 3];
  }
  int local = v0 + v1 + v2 + v3;
  sm[0][t] = local;
  __syncthreads();
  int pi = 0;
  for (int dd = 1; dd < 1024; dd <<= 1) {
    int v = sm[pi][t];
    if (t >= dd) v += sm[pi][t - dd];
    sm[pi ^ 1][t] = v;
    pi ^= 1;
    __syncthreads();
  }
  int pre = sm[pi][t] - local + bsum[blockIdx.x];
  if (base + 3 < n) {
    int4 o; o.x = pre; o.y = pre + v0; o.z = pre + v0 + v1; o.w = pre + v0 + v1 + v2;
    *(int4*)(out + base) = o;
  } else {
    if (base + 0 < n) out[base + 0] = pre;
    if (base + 1 < n) out[base + 1] = pre + v0;
    if (base + 2 < n) out[base + 2] = pre + v0 + v1;
    if (base + 3 < n) out[base + 3] = pre + v0 + v1 + v2;
  }
  if (blockIdx.x == 0 && t == 0) out[n] = bsum[gridDim.x];
}

__global__ void fill_csr_kernel(const int* __restrict__ ei, const int* __restrict__ ea,
                                const int* __restrict__ offs, int* __restrict__ cur,
                                int* __restrict__ packed) {
  int e = blockIdx.x * 256 + threadIdx.x;
  if (e >= NE) return;
  int dst = ei[NE + e];
  int pos = offs[dst] + atomicAdd(&cur[dst], 1);
  packed[pos] = (ei[e] & 0x1FFFF) | ((ea[2 * e] & 3) << 17) | ((ea[2 * e + 1] & 3) << 20);
}

// ---------------- aggregation + dynamic per-row i8 quantization ---------------
__global__ void agg_kernel(const unsigned short* __restrict__ h,
                           const int* __restrict__ offs,
                           const int* __restrict__ packed,
                           const float* __restrict__ be1,   // [8][512] layer slice
                           const float* __restrict__ be2,   // [4][512] layer slice
                           signed char* __restrict__ aq,    // [MPAD][512] i8
                           float* __restrict__ sa) {        // [MPAD] row scales
  int gid = blockIdx.x * 256 + threadIdx.x;
  int n = gid >> 6;
  if (n >= NN) return;
  int d0 = (gid & 63) << 3;
  float acc[8] = {0, 0, 0, 0, 0, 0, 0, 0};
  add8(acc, *(const uint4*)(h + (size_t)n * D + d0));
  addf8(acc, be1 + 6 * D + d0, 1.0f);
  addf8(acc, be2 + 3 * D + d0, 1.0f);
  int beg = offs[n], end = offs[n + 1];
  unsigned c0 = 0, c1 = 0;
  int i = beg;
  for (; i + 4 <= end; i += 4) {
    int p0 = packed[i], p1 = packed[i + 1], p2 = packed[i + 2], p3 = packed[i + 3];
    uint4 v0 = *(const uint4*)(h + (size_t)(p0 & 0x1FFFF) * D + d0);
    uint4 v1 = *(const uint4*)(h + (size_t)(p1 & 0x1FFFF) * D + d0);
    uint4 v2 = *(const uint4*)(h + (size_t)(p2 & 0x1FFFF) * D + d0);
    uint4 v3 = *(const uint4*)(h + (size_t)(p3 & 0x1FFFF) * D + d0);
    c0 += (1u << (((p0 >> 17) & 3) * 8)) + (1u << (((p1 >> 17) & 3) * 8)) +
          (1u << (((p2 >> 17) & 3) * 8)) + (1u << (((p3 >> 17) & 3) * 8));
    c1 += (1u << (((p0 >> 20) & 3) * 8)) + (1u << (((p1 >> 20) & 3) * 8)) +
          (1u << (((p2 >> 20) & 3) * 8)) + (1u << (((p3 >> 20) & 3) * 8));
    add8(acc, v0); add8(acc, v1); add8(acc, v2); add8(acc, v3);
  }
  for (; i < end; ++i) {
    int p = packed[i];
    c0 += 1u << (((p >> 17) & 3) * 8);
    c1 += 1u << (((p >> 20) & 3) * 8);
    add8(acc, *(const uint4*)(h + (size_t)(p & 0x1FFFF) * D + d0));
  }
  #pragma unroll
  for (int v = 0; v < 3; ++v) {
    float s0 = (float)((c0 >> (8 * v)) & 0xffu);
    float s1 = (float)((c1 >> (8 * v)) & 0xffu);
    if (s0 != 0.f) addf8(acc, be1 + v * D + d0, s0);
    if (s1 != 0.f) addf8(acc, be2 + v * D + d0, s1);
  }
  float mx = 0.f;
  #pragma unroll
  for (int j = 0; j < 8; ++j) mx = fmaxf(mx, fabsf(acc[j]));
  #pragma unroll
  for (int o = 32; o > 0; o >>= 1) mx = fmaxf(mx, __shfl_xor(mx, o));
  float s = mx * (1.0f / 127.0f);
  if (s < 1e-30f) s = 1e-30f;
  float inv = 1.0f / s;
  int q[8];
  #pragma unroll
  for (int j = 0; j < 8; ++j) q[j] = q8(acc[j], inv);
  uint2 pk;
  pk.x = (q[0] & 0xff) | ((q[1] & 0xff) << 8) | ((q[2] & 0xff) << 16) | ((q[3] & 0xff) << 24);
  pk.y = (q[4] & 0xff) | ((q[5] & 0xff) << 8) | ((q[6] & 0xff) << 16) | ((q[7] & 0xff) << 24);
  *(uint2*)(aq + (size_t)n * 512 + d0) = pk;
  if ((gid & 63) == 0) sa[n] = s;
}

// ---------------- mean pooling: one wave per graph ----------------------------
__global__ void pool_kernel(const unsigned short* __restrict__ h,
                            const int* __restrict__ goff,
                            unsigned short* __restrict__ pooled) {
  int gid = blockIdx.x * 256 + threadIdx.x;
  int g = gid >> 6;
  if (g >= NG) return;
  int d0 = (gid & 63) << 3;
  int beg = goff[g], end = goff[g + 1];
  float acc[8] = {0, 0, 0, 0, 0, 0, 0, 0};
  for (int nd = beg; nd < end; ++nd)
    add8(acc, *(const uint4*)(h + (size_t)nd * D + d0));
  int c = end - beg; if (c < 1) c = 1;
  float inv = 1.0f / (float)c;
  #pragma unroll
  for (int j = 0; j < 8; ++j) acc[j] *= inv;
  *(uint4*)(pooled + (size_t)g * D + d0) = pack8(acc);
}

// ---------------- f32 [R][C] -> bf16 [C][R] transpose (weights) ---------------
__global__ void transpose_bf16_kernel(const float* __restrict__ in,
                                      unsigned short* __restrict__ out,
                                      int R, int C) {
  __shared__ float tile[32][33];
  const float* inp = in + (size_t)blockIdx.z * R * C;
  unsigned short* outp = out + (size_t)blockIdx.z * R * C;
  int c0 = blockIdx.x * 32, r0 = blockIdx.y * 32;
  int tx = threadIdx.x, ty = threadIdx.y;  // (32, 8)
  #pragma unroll
  for (int j = 0; j < 32; j += 8)
    tile[ty + j][tx] = inp[(size_t)(r0 + ty + j) * C + (c0 + tx)];
  __syncthreads();
  #pragma unroll
  for (int j = 0; j < 32; j += 8)
    outp[(size_t)(c0 + ty + j) * R + (r0 + tx)] = f2bf(tile[tx][ty + j]);
}

// ---------------- W1 per-output-column absmax, split-K + atomicMax on bits ----
__global__ void wmax_kernel(const float* __restrict__ W, unsigned* __restrict__ swbits,
                            int K, int N) {
  int n = blockIdx.x * 256 + threadIdx.x;
  const float* Wl = W + (size_t)blockIdx.y * K * N;
  int kper = K / gridDim.z;
  int k0 = blockIdx.z * kper;
  float mx = 0.f;
  for (int k = k0; k < k0 + kper; ++k)
    mx = fmaxf(mx, fabsf(Wl[(size_t)k * N + n]));
  atomicMax(&swbits[(size_t)blockIdx.y * N + n], __float_as_uint(mx));
}

__global__ void scale_kernel(unsigned* __restrict__ swbits, int n) {
  int i = blockIdx.x * 256 + threadIdx.x;
  if (i >= n) return;
  float mx = __uint_as_float(swbits[i]);
  float s = mx * (1.0f / 127.0f);
  if (s < 1e-30f) s = 1e-30f;
  ((float*)swbits)[i] = s;
}

// ---------------- f32 [R][C] -> i8 [C][R] transpose + quant -------------------
__global__ void transpose_i8_kernel(const float* __restrict__ in,
                                    signed char* __restrict__ out,
                                    const float* __restrict__ sw,
                                    int R, int C) {
  __shared__ float tile[32][33];
  const float* inp = in + (size_t)blockIdx.z * R * C;
  signed char* outp = out + (size_t)blockIdx.z * R * C;
  const float* swp = sw + (size_t)blockIdx.z * C;
  int c0 = blockIdx.x * 32, r0 = blockIdx.y * 32;
  int tx = threadIdx.x, ty = threadIdx.y;  // (32, 8)
  #pragma unroll
  for (int j = 0; j < 32; j += 8)
    tile[ty + j][tx] = inp[(size_t)(r0 + ty + j) * C + (c0 + tx)];
  __syncthreads();
  #pragma unroll
  for (int j = 0; j < 32; j += 8) {
    int oc = c0 + ty + j;
    float inv = 1.0f / swp[oc];
    outp[(size_t)oc * R + (r0 + tx)] = (signed char)q8(tile[tx][ty + j], inv);
  }
}

// ---------------- NT bf16 MFMA GEMM (R6 K-loop + R9 LDS-staged C store) -------
// __launch_bounds__(256, 4): VGPR 84->56, occupancy 25->29%, 99.6->74 us (R12).
__global__ __launch_bounds__(256, 4) void gemm_nt(
    const unsigned short* __restrict__ A,
    const unsigned short* __restrict__ Bt,
    const float* __restrict__ bias,
    void* __restrict__ Cout,
    int K, int N, int gm, int gn, int relu, int out_f32) {
  __shared__ unsigned short SMEM[128 * 136];   // 34816 B
  unsigned short* Asm = SMEM;                  // 4096 elems
  unsigned short* Bsm = SMEM + 4096;           // 4096 elems
  const int tid = threadIdx.x;
  const int w = tid >> 6;
  const int lane = tid & 63;
  const int wm = w & 1, wn = w >> 1;

  int b = blockIdx.x;
  int band = b / (gn * 8);
  int r = b - band * (gn * 8);
  int bm = gm - band * 8; if (bm > 8) bm = 8;
  const long m0 = ((long)band * 8 + (r % bm)) * 128;
  const long n0 = (long)(r / bm) * 128;

  const unsigned short* Ag = A + (m0 + 32 * w + (lane >> 2)) * (long)K + (lane & 3) * 8;
  const unsigned short* Bg = Bt + (n0 + 32 * w + (lane >> 2)) * (long)K + (lane & 3) * 8;
  unsigned short* AsmW = Asm + 32 * w * 32;
  unsigned short* BsmW = Bsm + 32 * w * 32;
  const long rstep = 16l * K;

  const int frow = lane & 15;
  const int fcol = (lane >> 4) * 8;

  f32x4 acc[4][4];
  f32x4 zero = {0.f, 0.f, 0.f, 0.f};
  #pragma unroll
  for (int i = 0; i < 4; ++i)
    #pragma unroll
    for (int j = 0; j < 4; ++j) acc[i][j] = zero;

  for (int kt = 0; kt < K; kt += 32) {
    __syncthreads();
    gload_lds16(Ag + kt, AsmW);
    gload_lds16(Ag + kt + rstep, AsmW + 16 * 32);
    gload_lds16(Bg + kt, BsmW);
    gload_lds16(Bg + kt + rstep, BsmW + 16 * 32);
    __syncthreads();
    bf16x8 af[4], bfm[4];
    #pragma unroll
    for (int mt = 0; mt < 4; ++mt)
      af[mt] = *(const bf16x8*)(Asm + (wm * 64 + mt * 16 + frow) * 32 + fcol);
    #pragma unroll
    for (int nt = 0; nt < 4; ++nt)
      bfm[nt] = *(const bf16x8*)(Bsm + (wn * 64 + nt * 16 + frow) * 32 + fcol);
    #pragma unroll
    for (int mt = 0; mt < 4; ++mt)
      #pragma unroll
      for (int nt = 0; nt < 4; ++nt)
        acc[mt][nt] = __builtin_amdgcn_mfma_f32_16x16x32_bf16(bfm[nt], af[mt], acc[mt][nt], 0, 0, 0);
  }

  const int nq = (lane >> 4) * 4;
  if (out_f32) {
    #pragma unroll
    for (int mt = 0; mt < 4; ++mt) {
      long gm_ = m0 + wm * 64 + mt * 16 + frow;
      #pragma unroll
      for (int nt = 0; nt < 4; ++nt) {
        long gn_ = n0 + wn * 64 + nt * 16 + nq;
        float4 bv = *(const float4*)(bias + gn_);
        float v0 = acc[mt][nt][0] + bv.x;
        float v1 = acc[mt][nt][1] + bv.y;
        float v2 = acc[mt][nt][2] + bv.z;
        float v3 = acc[mt][nt][3] + bv.w;
        if (relu) {
          v0 = fmaxf(v0, 0.f); v1 = fmaxf(v1, 0.f);
          v2 = fmaxf(v2, 0.f); v3 = fmaxf(v3, 0.f);
        }
        float4 o = {v0, v1, v2, v3};
        *(float4*)((float*)Cout + gm_ * (long)N + gn_) = o;
      }
    }
  } else {
    __syncthreads();   // staging LDS no longer needed; reuse as C tile
    #pragma unroll
    for (int mt = 0; mt < 4; ++mt) {
      int ml = wm * 64 + mt * 16 + frow;
      #pragma unroll
      for (int nt = 0; nt < 4; ++nt) {
        int nl = wn * 64 + nt * 16 + nq;
        float4 bv = *(const float4*)(bias + n0 + nl);
        float v0 = acc[mt][nt][0] + bv.x;
        float v1 = acc[mt][nt][1] + bv.y;
        float v2 = acc[mt][nt][2] + bv.z;
        float v3 = acc[mt][nt][3] + bv.w;
        if (relu) {
          v0 = fmaxf(v0, 0.f); v1 = fmaxf(v1, 0.f);
          v2 = fmaxf(v2, 0.f); v3 = fmaxf(v3, 0.f);
        }
        u16x4 o = {f2bf(v0), f2bf(v1), f2bf(v2), f2bf(v3)};
        *(u16x4*)(SMEM + ml * 136 + nl) = o;
      }
    }
    __syncthreads();
    unsigned short* Cg = (unsigned short*)Cout;
    #pragma unroll
    for (int p = 0; p < 8; ++p) {
      int row = p * 16 + (tid >> 4);
      int col = (tid & 15) * 8;
      uint4 v = *(const uint4*)(SMEM + row * 136 + col);
      *(uint4*)(Cg + (m0 + row) * (long)N + n0 + col) = v;
    }
  }
}

// ---------------- NT i8 MFMA GEMM (16x16x64_i8, BK=64, LDS-staged C store) ----
// __launch_bounds__(256, 4): same occupancy lever as gemm_nt (R12-validated).
__global__ __launch_bounds__(256, 4) void gemm_nt_i8(
    const signed char* __restrict__ A,   // [M][K] i8
    const signed char* __restrict__ Bt,  // [N][K] i8
    const float* __restrict__ sa,        // [M]
    const float* __restrict__ sb,        // [N]
    const float* __restrict__ bias,      // [N]
    unsigned short* __restrict__ Cout,
    int K, int N, int gm, int gn, int relu) {
  __shared__ unsigned short SMEM[128 * 136];   // 34816 B (staging uses first 16KB)
  signed char* Asm = (signed char*)SMEM;       // 8192 B
  signed char* Bsm = Asm + 8192;               // 8192 B
  const int tid = threadIdx.x;
  const int w = tid >> 6;
  const int lane = tid & 63;
  const int wm = w & 1, wn = w >> 1;

  int b = blockIdx.x;
  int band = b / (gn * 8);
  int r = b - band * (gn * 8);
  int bm = gm - band * 8; if (bm > 8) bm = 8;
  const long m0 = ((long)band * 8 + (r % bm)) * 128;
  const long n0 = (long)(r / bm) * 128;

  const signed char* Ag = A + (m0 + 32 * w + (lane >> 2)) * (long)K + (lane & 3) * 16;
  const signed char* Bg = Bt + (n0 + 32 * w + (lane >> 2)) * (long)K + (lane & 3) * 16;
  signed char* AsmW = Asm + 32 * w * 64;
  signed char* BsmW = Bsm + 32 * w * 64;
  const long rstep = 16l * K;

  const int frow = lane & 15;
  const int fcol = (lane >> 4) * 16;

  i32x4 acc[4][4];
  i32x4 zero = {0, 0, 0, 0};
  #pragma unroll
  for (int i = 0; i < 4; ++i)
    #pragma unroll
    for (int j = 0; j < 4; ++j) acc[i][j] = zero;

  for (int kt = 0; kt < K; kt += 64) {
    __syncthreads();
    gload_lds16b(Ag + kt, AsmW);
    gload_lds16b(Ag + kt + rstep, AsmW + 16 * 64);
    gload_lds16b(Bg + kt, BsmW);
    gload_lds16b(Bg + kt + rstep, BsmW + 16 * 64);
    __syncthreads();
    i32x4 af[4], bfm[4];
    #pragma unroll
    for (int mt = 0; mt < 4; ++mt)
      af[mt] = *(const i32x4*)(Asm + (wm * 64 + mt * 16 + frow) * 64 + fcol);
    #pragma unroll
    for (int nt = 0; nt < 4; ++nt)
      bfm[nt] = *(const i32x4*)(Bsm + (wn * 64 + nt * 16 + frow) * 64 + fcol);
    #pragma unroll
    for (int mt = 0; mt < 4; ++mt)
      #pragma unroll
      for (int nt = 0; nt < 4; ++nt)
        acc[mt][nt] = __builtin_amdgcn_mfma_i32_16x16x64_i8(bfm[nt], af[mt], acc[mt][nt], 0, 0, 0);
  }

  const int nq = (lane >> 4) * 4;
  __syncthreads();   // staging LDS no longer needed; reuse as C tile
  #pragma unroll
  for (int mt = 0; mt < 4; ++mt) {
    int ml = wm * 64 + mt * 16 + frow;
    float sam = sa[m0 + ml];
    #pragma unroll
    for (int nt = 0; nt < 4; ++nt) {
      int nl = wn * 64 + nt * 16 + nq;
      float4 bv = *(const float4*)(bias + n0 + nl);
      float4 sbv = *(const float4*)(sb + n0 + nl);
      float v0 = (float)acc[mt][nt][0] * (sam * sbv.x) + bv.x;
      float v1 = (float)acc[mt][nt][1] * (sam * sbv.y) + bv.y;
      float v2 = (float)acc[mt][nt][2] * (sam * sbv.z) + bv.z;
      float v3 = (float)acc[mt][nt][3] * (sam * sbv.w) + bv.w;
      if (relu) {
        v0 = fmaxf(v0, 0.f); v1 = fmaxf(v1, 0.f);
        v2 = fmaxf(v2, 0.f); v3 = fmaxf(v3, 0.f);
      }
      u16x4 o = {f2bf(v0), f2bf(v1), f2bf(v2), f2bf(v3)};
      *(u16x4*)(SMEM + ml * 136 + nl) = o;
    }
  }
  __syncthreads();
  #pragma unroll
  for (int p = 0; p < 8; ++p) {
    int row = p * 16 + (tid >> 4);
    int col = (tid & 15) * 8;
    uint4 v = *(const uint4*)(SMEM + row * 136 + col);
    *(uint4*)(Cout + (m0 + row) * (long)N + n0 + col) = v;
  }
}

extern "C" void kernel_launch(void* const* d_in, const int* in_sizes, int n_in,
                              void* d_out, int out_size, void* d_ws, size_t ws_size,
                              hipStream_t stream) {
  (void)in_sizes; (void)n_in; (void)out_size; (void)ws_size;
  const int*   x          = (const int*)d_in[0];
  const int*   edge_index = (const int*)d_in[1];
  const int*   edge_attr  = (const int*)d_in[2];
  const int*   batch      = (const int*)d_in[3];
  const float* atom_emb1  = (const float*)d_in[4];
  const float* atom_emb2  = (const float*)d_in[5];
  const float* bond_emb1  = (const float*)d_in[6];   // [5][8][512]
  const float* bond_emb2  = (const float*)d_in[7];   // [5][4][512]
  const float* W1         = (const float*)d_in[8];   // [5][512][1024]
  const float* b1         = (const float*)d_in[9];   // [5][1024]
  const float* W2         = (const float*)d_in[10];  // [5][1024][512]
  const float* b2         = (const float*)d_in[11];  // [5][512]
  const float* pW1        = (const float*)d_in[12];  // [512][512]
  const float* pb1        = (const float*)d_in[13];
  const float* pW2        = (const float*)d_in[14];
  const float* pb2        = (const float*)d_in[15];

  // ---- workspace layout ----
  unsigned short* h      = (unsigned short*)d_ws;                 // MPAD*D bf16
  unsigned short* hidden = h + (size_t)MPAD * D;                  // MPAD*H2 bf16
  unsigned short* w2t    = hidden + (size_t)MPAD * H2;            // NL*D*H2 bf16
  unsigned short* pw1t   = w2t + (size_t)NL * D * H2;             // D*D
  unsigned short* pw2t   = pw1t + (size_t)D * D;                  // D*D
  unsigned short* pooled = pw2t + (size_t)D * D;                  // NG*D
  unsigned short* zmid   = pooled + (size_t)NG * D;               // NG*D
  signed char* aq  = (signed char*)(zmid + (size_t)NG * D);       // MPAD*512 i8
  signed char* w1q = aq + (size_t)MPAD * 512;                     // NL*H2*512 i8
  float* sa  = (float*)(w1q + (size_t)NL * H2 * 512);             // MPAD
  float* sw1 = sa + MPAD;                                         // NL*H2 (zero-init)
  int* indeg  = (int*)(sw1 + NL * H2);                            // NN+1 (zero-init)
  int* cur    = indeg + (NN + 1);                                 // NN   (zero-init)
  int* gcnt   = cur + NN;                                         // NG   (zero-init)
  int* offs   = gcnt + NG;                                        // NN+1
  int* goff   = offs + (NN + 1);                                  // NG+1
  int* packed = goff + (NG + 1);                                  // NE
  int* bsum   = packed + NE;                                      // 64

  // zero sw1 (absmax accum) + counters in one memset (adjacent)
  (void)hipMemsetAsync(sw1, 0, ((size_t)NL * H2 + (NN + 1) + NN + NG) * 4, stream);

  // W1 -> i8 [n][k] + per-col scales (split-K absmax, bit-pattern atomicMax)
  wmax_kernel<<<dim3(H2 / 256, NL, 16), 256, 0, stream>>>(W1, (unsigned*)sw1, D, H2);
  scale_kernel<<<(NL * H2 + 255) / 256, 256, 0, stream>>>((unsigned*)sw1, NL * H2);
  transpose_i8_kernel<<<dim3(H2 / 32, D / 32, NL), dim3(32, 8), 0, stream>>>(W1, w1q, sw1, D, H2);
  transpose_bf16_kernel<<<dim3(D / 32, H2 / 32, NL), dim3(32, 8), 0, stream>>>(W2, w2t, H2, D);
  transpose_bf16_kernel<<<dim3(D / 32, D / 32, 1), dim3(32, 8), 0, stream>>>(pW1, pw1t, D, D);
  transpose_bf16_kernel<<<dim3(D / 32, D / 32, 1), dim3(32, 8), 0, stream>>>(pW2, pw2t, D, D);

  atom_enc_kernel<<<(NN * 64) / 256, 256, 0, stream>>>(x, atom_emb1, atom_emb2, h);

  // CSR over dst (multi-block scan)
  const int B1 = (NN + 4095) / 4096;   // 13
  count_kernel<<<(NE + 255) / 256, 256, 0, stream>>>(edge_index + NE, indeg, NE);
  scan_sums_kernel<<<B1, 1024, 0, stream>>>(indeg, bsum, NN);
  scan_partials_kernel<<<1, 64, 0, stream>>>(bsum, B1);
  scan_final_kernel<<<B1, 1024, 0, stream>>>(indeg, bsum, offs, NN);
  fill_csr_kernel<<<(NE + 255) / 256, 256, 0, stream>>>(edge_index, edge_attr, offs, cur, packed);

  // graph ranges (batch is sorted)
  const int B2 = (NG + 4095) / 4096;   // 1
  count_kernel<<<(NN + 255) / 256, 256, 0, stream>>>(batch, gcnt, NN);
  scan_sums_kernel<<<B2, 1024, 0, stream>>>(gcnt, bsum, NG);
  scan_partials_kernel<<<1, 64, 0, stream>>>(bsum, B2);
  scan_final_kernel<<<B2, 1024, 0, stream>>>(gcnt, bsum, goff, NG);

  const int GM = MPAD / 128;  // 391
  for (int l = 0; l < NL; ++l) {
    agg_kernel<<<(NN * 64) / 256, 256, 0, stream>>>(
        h, offs, packed, bond_emb1 + (size_t)l * 8 * D, bond_emb2 + (size_t)l * 4 * D, aq, sa);
    gemm_nt_i8<<<GM * (H2 / 128), 256, 0, stream>>>(
        aq, w1q + (size_t)l * H2 * 512, sa, sw1 + (size_t)l * H2, b1 + (size_t)l * H2,
        hidden, D, H2, GM, H2 / 128, 1);
    gemm_nt<<<GM * (D / 128), 256, 0, stream>>>(
        hidden, w2t + (size_t)l * D * H2, b2 + (size_t)l * D, h,
        H2, D, GM, D / 128, (l < NL - 1) ? 1 : 0, 0);
  }

  pool_kernel<<<(NG * 64) / 256, 256, 0, stream>>>(h, goff, pooled);
  gemm_nt<<<(NG / 128) * (D / 128), 256, 0, stream>>>(
      pooled, pw1t, pb1, zmid, D, D, NG / 128, D / 128, 1, 0);
  gemm_nt<<<(NG / 128) * (D / 128), 256, 0, stream>>>(
      zmid, pw2t, pb2, (float*)d_out, D, D, NG / 128, D / 128, 0, 1);
}

// Round 14
// 980.074 us; speedup vs baseline: 1.4583x; 1.0094x over previous
//
#include <hip/hip_runtime.h>

#define NN 50000
#define NE 200000
#define NG 2048
#define D  512
#define H2 1024
#define NL 5
#define MPAD 50048   // 391 * 128

typedef __attribute__((ext_vector_type(8))) short bf16x8;
typedef __attribute__((ext_vector_type(4))) float f32x4;
typedef __attribute__((ext_vector_type(4))) int i32x4;
typedef __attribute__((ext_vector_type(4))) unsigned short u16x4;

__device__ __forceinline__ float bf2f(unsigned b) {
  union { unsigned u; float f; } c; c.u = b << 16; return c.f;
}
__device__ __forceinline__ unsigned short f2bf(float f) {
  union { float f; unsigned u; } c; c.f = f;
  return (unsigned short)((c.u + 0x7FFFu + ((c.u >> 16) & 1u)) >> 16);
}
__device__ __forceinline__ void add8(float* acc, uint4 v) {
  acc[0] += bf2f(v.x & 0xffffu); acc[1] += bf2f(v.x >> 16);
  acc[2] += bf2f(v.y & 0xffffu); acc[3] += bf2f(v.y >> 16);
  acc[4] += bf2f(v.z & 0xffffu); acc[5] += bf2f(v.z >> 16);
  acc[6] += bf2f(v.w & 0xffffu); acc[7] += bf2f(v.w >> 16);
}
__device__ __forceinline__ void addf8(float* acc, const float* p, float s) {
  float4 a = *(const float4*)p;
  float4 b = *(const float4*)(p + 4);
  acc[0] += s * a.x; acc[1] += s * a.y; acc[2] += s * a.z; acc[3] += s * a.w;
  acc[4] += s * b.x; acc[5] += s * b.y; acc[6] += s * b.z; acc[7] += s * b.w;
}
__device__ __forceinline__ uint4 pack8(const float* acc) {
  uint4 v;
  v.x = (unsigned)f2bf(acc[0]) | ((unsigned)f2bf(acc[1]) << 16);
  v.y = (unsigned)f2bf(acc[2]) | ((unsigned)f2bf(acc[3]) << 16);
  v.z = (unsigned)f2bf(acc[4]) | ((unsigned)f2bf(acc[5]) << 16);
  v.w = (unsigned)f2bf(acc[6]) | ((unsigned)f2bf(acc[7]) << 16);
  return v;
}
__device__ __forceinline__ void gload_lds16(const unsigned short* g, unsigned short* l) {
  __builtin_amdgcn_global_load_lds(
      (const __attribute__((address_space(1))) void*)g,
      (__attribute__((address_space(3))) void*)l, 16, 0, 0);
}
__device__ __forceinline__ void gload_lds16b(const signed char* g, signed char* l) {
  __builtin_amdgcn_global_load_lds(
      (const __attribute__((address_space(1))) void*)g,
      (__attribute__((address_space(3))) void*)l, 16, 0, 0);
}
__device__ __forceinline__ int q8(float v, float inv) {
  int q = (int)rintf(v * inv);
  if (q > 127) q = 127;
  if (q < -127) q = -127;
  return q;
}

// ---------------- atom encoder: h[n] = ae1[x0] + ae2[x1]  (bf16 out) ----------
__global__ void atom_enc_kernel(const int* __restrict__ x,
                                const float* __restrict__ ae1,
                                const float* __restrict__ ae2,
                                unsigned short* __restrict__ h) {
  int gid = blockIdx.x * 256 + threadIdx.x;
  int n = gid >> 6;
  if (n >= NN) return;
  int d0 = (gid & 63) << 3;
  int x0 = x[2 * n], x1 = x[2 * n + 1];
  float acc[8] = {0, 0, 0, 0, 0, 0, 0, 0};
  addf8(acc, ae1 + (size_t)x0 * D + d0, 1.0f);
  addf8(acc, ae2 + (size_t)x1 * D + d0, 1.0f);
  *(uint4*)(h + (size_t)n * D + d0) = pack8(acc);
}

// ---------------- CSR build ---------------------------------------------------
__global__ void count_kernel(const int* __restrict__ keys, int* __restrict__ cnt, int n) {
  int i = blockIdx.x * 256 + threadIdx.x;
  if (i < n) atomicAdd(&cnt[keys[i]], 1);
}

// ---- 3-phase multi-block exclusive scan (4096 elems/block, int4-coalesced) ---
__global__ void scan_sums_kernel(const int* __restrict__ in, int* __restrict__ bsum, int n) {
  __shared__ int sm[1024];
  int t = threadIdx.x;
  int base = blockIdx.x * 4096 + t * 4;
  int s = 0;
  if (base + 3 < n) {
    int4 v = *(const int4*)(in + base);
    s = v.x + v.y + v.z + v.w;
  } else {
    for (int i = 0; i < 4; ++i) if (base + i < n) s += in[base + i];
  }
  sm[t] = s;
  __syncthreads();
  for (int d = 512; d > 0; d >>= 1) {
    if (t < d) sm[t] += sm[t + d];
    __syncthreads();
  }
  if (t == 0) bsum[blockIdx.x] = sm[0];
}

__global__ void scan_partials_kernel(int* __restrict__ bsum, int B) {
  if (threadIdx.x == 0 && blockIdx.x == 0) {
    int run = 0;
    for (int i = 0; i < B; ++i) { int v = bsum[i]; bsum[i] = run; run += v; }
    bsum[B] = run;
  }
}

__global__ void scan_final_kernel(const int* __restrict__ in, const int* __restrict__ bsum,
                                  int* __restrict__ out, int n) {
  __shared__ int sm[2][1024];
  int t = threadIdx.x;
  int base = blockIdx.x * 4096 + t * 4;
  int v0 = 0, v1 = 0, v2 = 0, v3 = 0;
  if (base + 3 < n) {
    int4 v = *(const int4*)(in + base);
    v0 = v.x; v1 = v.y; v2 = v.z; v3 = v.w;
  } else {
    if (base + 0 < n) v0 = in[base + 0];
    if (base + 1 < n) v1 = in[base + 1];
    if (base + 2 < n) v2 = in[base + 2];
    if (base + 3 < n) v3 = in[base + 3];
  }
  int local = v0 + v1 + v2 + v3;
  sm[0][t] = local;
  __syncthreads();
  int pi = 0;
  for (int dd = 1; dd < 1024; dd <<= 1) {
    int v = sm[pi][t];
    if (t >= dd) v += sm[pi][t - dd];
    sm[pi ^ 1][t] = v;
    pi ^= 1;
    __syncthreads();
  }
  int pre = sm[pi][t] - local + bsum[blockIdx.x];
  if (base + 3 < n) {
    int4 o; o.x = pre; o.y = pre + v0; o.z = pre + v0 + v1; o.w = pre + v0 + v1 + v2;
    *(int4*)(out + base) = o;
  } else {
    if (base + 0 < n) out[base + 0] = pre;
    if (base + 1 < n) out[base + 1] = pre + v0;
    if (base + 2 < n) out[base + 2] = pre + v0 + v1;
    if (base + 3 < n) out[base + 3] = pre + v0 + v1 + v2;
  }
  if (blockIdx.x == 0 && t == 0) out[n] = bsum[gridDim.x];
}

__global__ void fill_csr_kernel(const int* __restrict__ ei, const int* __restrict__ ea,
                                const int* __restrict__ offs, int* __restrict__ cur,
                                int* __restrict__ packed) {
  int e = blockIdx.x * 256 + threadIdx.x;
  if (e >= NE) return;
  int dst = ei[NE + e];
  int pos = offs[dst] + atomicAdd(&cur[dst], 1);
  packed[pos] = (ei[e] & 0x1FFFF) | ((ea[2 * e] & 3) << 17) | ((ea[2 * e + 1] & 3) << 20);
}

// ---------------- aggregation + dynamic per-row i8 quantization ---------------
__global__ void agg_kernel(const unsigned short* __restrict__ h,
                           const int* __restrict__ offs,
                           const int* __restrict__ packed,
                           const float* __restrict__ be1,   // [8][512] layer slice
                           const float* __restrict__ be2,   // [4][512] layer slice
                           signed char* __restrict__ aq,    // [MPAD][512] i8
                           float* __restrict__ sa) {        // [MPAD] row scales
  int gid = blockIdx.x * 256 + threadIdx.x;
  int n = gid >> 6;
  if (n >= NN) return;
  int d0 = (gid & 63) << 3;
  float acc[8] = {0, 0, 0, 0, 0, 0, 0, 0};
  add8(acc, *(const uint4*)(h + (size_t)n * D + d0));
  addf8(acc, be1 + 6 * D + d0, 1.0f);
  addf8(acc, be2 + 3 * D + d0, 1.0f);
  int beg = offs[n], end = offs[n + 1];
  unsigned c0 = 0, c1 = 0;
  int i = beg;
  for (; i + 4 <= end; i += 4) {
    int p0 = packed[i], p1 = packed[i + 1], p2 = packed[i + 2], p3 = packed[i + 3];
    uint4 v0 = *(const uint4*)(h + (size_t)(p0 & 0x1FFFF) * D + d0);
    uint4 v1 = *(const uint4*)(h + (size_t)(p1 & 0x1FFFF) * D + d0);
    uint4 v2 = *(const uint4*)(h + (size_t)(p2 & 0x1FFFF) * D + d0);
    uint4 v3 = *(const uint4*)(h + (size_t)(p3 & 0x1FFFF) * D + d0);
    c0 += (1u << (((p0 >> 17) & 3) * 8)) + (1u << (((p1 >> 17) & 3) * 8)) +
          (1u << (((p2 >> 17) & 3) * 8)) + (1u << (((p3 >> 17) & 3) * 8));
    c1 += (1u << (((p0 >> 20) & 3) * 8)) + (1u << (((p1 >> 20) & 3) * 8)) +
          (1u << (((p2 >> 20) & 3) * 8)) + (1u << (((p3 >> 20) & 3) * 8));
    add8(acc, v0); add8(acc, v1); add8(acc, v2); add8(acc, v3);
  }
  for (; i < end; ++i) {
    int p = packed[i];
    c0 += 1u << (((p >> 17) & 3) * 8);
    c1 += 1u << (((p >> 20) & 3) * 8);
    add8(acc, *(const uint4*)(h + (size_t)(p & 0x1FFFF) * D + d0));
  }
  #pragma unroll
  for (int v = 0; v < 3; ++v) {
    float s0 = (float)((c0 >> (8 * v)) & 0xffu);
    float s1 = (float)((c1 >> (8 * v)) & 0xffu);
    if (s0 != 0.f) addf8(acc, be1 + v * D + d0, s0);
    if (s1 != 0.f) addf8(acc, be2 + v * D + d0, s1);
  }
  float mx = 0.f;
  #pragma unroll
  for (int j = 0; j < 8; ++j) mx = fmaxf(mx, fabsf(acc[j]));
  #pragma unroll
  for (int o = 32; o > 0; o >>= 1) mx = fmaxf(mx, __shfl_xor(mx, o));
  float s = mx * (1.0f / 127.0f);
  if (s < 1e-30f) s = 1e-30f;
  float inv = 1.0f / s;
  int q[8];
  #pragma unroll
  for (int j = 0; j < 8; ++j) q[j] = q8(acc[j], inv);
  uint2 pk;
  pk.x = (q[0] & 0xff) | ((q[1] & 0xff) << 8) | ((q[2] & 0xff) << 16) | ((q[3] & 0xff) << 24);
  pk.y = (q[4] & 0xff) | ((q[5] & 0xff) << 8) | ((q[6] & 0xff) << 16) | ((q[7] & 0xff) << 24);
  *(uint2*)(aq + (size_t)n * 512 + d0) = pk;
  if ((gid & 63) == 0) sa[n] = s;
}

// ---------------- mean pooling: one wave per graph ----------------------------
__global__ void pool_kernel(const unsigned short* __restrict__ h,
                            const int* __restrict__ goff,
                            unsigned short* __restrict__ pooled) {
  int gid = blockIdx.x * 256 + threadIdx.x;
  int g = gid >> 6;
  if (g >= NG) return;
  int d0 = (gid & 63) << 3;
  int beg = goff[g], end = goff[g + 1];
  float acc[8] = {0, 0, 0, 0, 0, 0, 0, 0};
  for (int nd = beg; nd < end; ++nd)
    add8(acc, *(const uint4*)(h + (size_t)nd * D + d0));
  int c = end - beg; if (c < 1) c = 1;
  float inv = 1.0f / (float)c;
  #pragma unroll
  for (int j = 0; j < 8; ++j) acc[j] *= inv;
  *(uint4*)(pooled + (size_t)g * D + d0) = pack8(acc);
}

// ---------------- f32 [R][C] -> bf16 [C][R] transpose (weights) ---------------
__global__ void transpose_bf16_kernel(const float* __restrict__ in,
                                      unsigned short* __restrict__ out,
                                      int R, int C) {
  __shared__ float tile[32][33];
  const float* inp = in + (size_t)blockIdx.z * R * C;
  unsigned short* outp = out + (size_t)blockIdx.z * R * C;
  int c0 = blockIdx.x * 32, r0 = blockIdx.y * 32;
  int tx = threadIdx.x, ty = threadIdx.y;  // (32, 8)
  #pragma unroll
  for (int j = 0; j < 32; j += 8)
    tile[ty + j][tx] = inp[(size_t)(r0 + ty + j) * C + (c0 + tx)];
  __syncthreads();
  #pragma unroll
  for (int j = 0; j < 32; j += 8)
    outp[(size_t)(c0 + ty + j) * R + (r0 + tx)] = f2bf(tile[tx][ty + j]);
}

// ---------------- W1 per-output-column absmax, split-K + atomicMax on bits ----
__global__ void wmax_kernel(const float* __restrict__ W, unsigned* __restrict__ swbits,
                            int K, int N) {
  int n = blockIdx.x * 256 + threadIdx.x;
  const float* Wl = W + (size_t)blockIdx.y * K * N;
  int kper = K / gridDim.z;
  int k0 = blockIdx.z * kper;
  float mx = 0.f;
  for (int k = k0; k < k0 + kper; ++k)
    mx = fmaxf(mx, fabsf(Wl[(size_t)k * N + n]));
  atomicMax(&swbits[(size_t)blockIdx.y * N + n], __float_as_uint(mx));
}

__global__ void scale_kernel(unsigned* __restrict__ swbits, int n) {
  int i = blockIdx.x * 256 + threadIdx.x;
  if (i >= n) return;
  float mx = __uint_as_float(swbits[i]);
  float s = mx * (1.0f / 127.0f);
  if (s < 1e-30f) s = 1e-30f;
  ((float*)swbits)[i] = s;
}

// ---------------- f32 [R][C] -> i8 [C][R] transpose + quant -------------------
__global__ void transpose_i8_kernel(const float* __restrict__ in,
                                    signed char* __restrict__ out,
                                    const float* __restrict__ sw,
                                    int R, int C) {
  __shared__ float tile[32][33];
  const float* inp = in + (size_t)blockIdx.z * R * C;
  signed char* outp = out + (size_t)blockIdx.z * R * C;
  const float* swp = sw + (size_t)blockIdx.z * C;
  int c0 = blockIdx.x * 32, r0 = blockIdx.y * 32;
  int tx = threadIdx.x, ty = threadIdx.y;  // (32, 8)
  #pragma unroll
  for (int j = 0; j < 32; j += 8)
    tile[ty + j][tx] = inp[(size_t)(r0 + ty + j) * C + (c0 + tx)];
  __syncthreads();
  #pragma unroll
  for (int j = 0; j < 32; j += 8) {
    int oc = c0 + ty + j;
    float inv = 1.0f / swp[oc];
    outp[(size_t)oc * R + (r0 + tx)] = (signed char)q8(tile[tx][ty + j], inv);
  }
}

// ---------------- NT bf16 MFMA GEMM -------------------------------------------
// R13 structure + 2x K-unroll: two proven BK=32 stage-pairs per barrier pair
// (4 staging buffers, 32KB, unioned under the 34.8KB C tile). Halves barrier
// count (K=1024: 32->16 drains) without touching any staging/frag/LDS mapping.
// __launch_bounds__(256, 4): VGPR cap for 4 waves/SIMD (R12-validated).
__global__ __launch_bounds__(256, 4) void gemm_nt(
    const unsigned short* __restrict__ A,
    const unsigned short* __restrict__ Bt,
    const float* __restrict__ bias,
    void* __restrict__ Cout,
    int K, int N, int gm, int gn, int relu, int out_f32) {
  __shared__ unsigned short SMEM[128 * 136];   // 34816 B
  unsigned short* Asm0 = SMEM;                 // 4096 elems each
  unsigned short* Bsm0 = SMEM + 4096;
  unsigned short* Asm1 = SMEM + 8192;
  unsigned short* Bsm1 = SMEM + 12288;
  const int tid = threadIdx.x;
  const int w = tid >> 6;
  const int lane = tid & 63;
  const int wm = w & 1, wn = w >> 1;

  int b = blockIdx.x;
  int band = b / (gn * 8);
  int r = b - band * (gn * 8);
  int bm = gm - band * 8; if (bm > 8) bm = 8;
  const long m0 = ((long)band * 8 + (r % bm)) * 128;
  const long n0 = (long)(r / bm) * 128;

  const unsigned short* Ag = A + (m0 + 32 * w + (lane >> 2)) * (long)K + (lane & 3) * 8;
  const unsigned short* Bg = Bt + (n0 + 32 * w + (lane >> 2)) * (long)K + (lane & 3) * 8;
  const int woff = 32 * w * 32;   // per-wave staging offset (elems)
  const long rstep = 16l * K;

  const int frow = lane & 15;
  const int fcol = (lane >> 4) * 8;
  const int aoff = (wm * 64 + frow) * 32 + fcol;   // + mt*16*32
  const int boff = (wn * 64 + frow) * 32 + fcol;   // + nt*16*32

  f32x4 acc[4][4];
  f32x4 zero = {0.f, 0.f, 0.f, 0.f};
  #pragma unroll
  for (int i = 0; i < 4; ++i)
    #pragma unroll
    for (int j = 0; j < 4; ++j) acc[i][j] = zero;

  for (int kt = 0; kt < K; kt += 64) {
    __syncthreads();
    gload_lds16(Ag + kt, Asm0 + woff);
    gload_lds16(Ag + kt + rstep, Asm0 + woff + 512);
    gload_lds16(Bg + kt, Bsm0 + woff);
    gload_lds16(Bg + kt + rstep, Bsm0 + woff + 512);
    gload_lds16(Ag + kt + 32, Asm1 + woff);
    gload_lds16(Ag + kt + 32 + rstep, Asm1 + woff + 512);
    gload_lds16(Bg + kt + 32, Bsm1 + woff);
    gload_lds16(Bg + kt + 32 + rstep, Bsm1 + woff + 512);
    __syncthreads();
    {
      bf16x8 af[4], bfm[4];
      #pragma unroll
      for (int mt = 0; mt < 4; ++mt)
        af[mt] = *(const bf16x8*)(Asm0 + aoff + mt * 512);
      #pragma unroll
      for (int nt = 0; nt < 4; ++nt)
        bfm[nt] = *(const bf16x8*)(Bsm0 + boff + nt * 512);
      #pragma unroll
      for (int mt = 0; mt < 4; ++mt)
        #pragma unroll
        for (int nt = 0; nt < 4; ++nt)
          acc[mt][nt] = __builtin_amdgcn_mfma_f32_16x16x32_bf16(bfm[nt], af[mt], acc[mt][nt], 0, 0, 0);
    }
    {
      bf16x8 af[4], bfm[4];
      #pragma unroll
      for (int mt = 0; mt < 4; ++mt)
        af[mt] = *(const bf16x8*)(Asm1 + aoff + mt * 512);
      #pragma unroll
      for (int nt = 0; nt < 4; ++nt)
        bfm[nt] = *(const bf16x8*)(Bsm1 + boff + nt * 512);
      #pragma unroll
      for (int mt = 0; mt < 4; ++mt)
        #pragma unroll
        for (int nt = 0; nt < 4; ++nt)
          acc[mt][nt] = __builtin_amdgcn_mfma_f32_16x16x32_bf16(bfm[nt], af[mt], acc[mt][nt], 0, 0, 0);
    }
  }

  const int nq = (lane >> 4) * 4;
  if (out_f32) {
    #pragma unroll
    for (int mt = 0; mt < 4; ++mt) {
      long gm_ = m0 + wm * 64 + mt * 16 + frow;
      #pragma unroll
      for (int nt = 0; nt < 4; ++nt) {
        long gn_ = n0 + wn * 64 + nt * 16 + nq;
        float4 bv = *(const float4*)(bias + gn_);
        float v0 = acc[mt][nt][0] + bv.x;
        float v1 = acc[mt][nt][1] + bv.y;
        float v2 = acc[mt][nt][2] + bv.z;
        float v3 = acc[mt][nt][3] + bv.w;
        if (relu) {
          v0 = fmaxf(v0, 0.f); v1 = fmaxf(v1, 0.f);
          v2 = fmaxf(v2, 0.f); v3 = fmaxf(v3, 0.f);
        }
        float4 o = {v0, v1, v2, v3};
        *(float4*)((float*)Cout + gm_ * (long)N + gn_) = o;
      }
    }
  } else {
    __syncthreads();   // staging LDS no longer needed; reuse as C tile
    #pragma unroll
    for (int mt = 0; mt < 4; ++mt) {
      int ml = wm * 64 + mt * 16 + frow;
      #pragma unroll
      for (int nt = 0; nt < 4; ++nt) {
        int nl = wn * 64 + nt * 16 + nq;
        float4 bv = *(const float4*)(bias + n0 + nl);
        float v0 = acc[mt][nt][0] + bv.x;
        float v1 = acc[mt][nt][1] + bv.y;
        float v2 = acc[mt][nt][2] + bv.z;
        float v3 = acc[mt][nt][3] + bv.w;
        if (relu) {
          v0 = fmaxf(v0, 0.f); v1 = fmaxf(v1, 0.f);
          v2 = fmaxf(v2, 0.f); v3 = fmaxf(v3, 0.f);
        }
        u16x4 o = {f2bf(v0), f2bf(v1), f2bf(v2), f2bf(v3)};
        *(u16x4*)(SMEM + ml * 136 + nl) = o;
      }
    }
    __syncthreads();
    unsigned short* Cg = (unsigned short*)Cout;
    #pragma unroll
    for (int p = 0; p < 8; ++p) {
      int row = p * 16 + (tid >> 4);
      int col = (tid & 15) * 8;
      uint4 v = *(const uint4*)(SMEM + row * 136 + col);
      *(uint4*)(Cg + (m0 + row) * (long)N + n0 + col) = v;
    }
  }
}

// ---------------- NT i8 MFMA GEMM (16x16x64_i8, BK=64, LDS-staged C store) ----
__global__ __launch_bounds__(256, 4) void gemm_nt_i8(
    const signed char* __restrict__ A,   // [M][K] i8
    const signed char* __restrict__ Bt,  // [N][K] i8
    const float* __restrict__ sa,        // [M]
    const float* __restrict__ sb,        // [N]
    const float* __restrict__ bias,      // [N]
    unsigned short* __restrict__ Cout,
    int K, int N, int gm, int gn, int relu) {
  __shared__ unsigned short SMEM[128 * 136];   // 34816 B (staging uses first 16KB)
  signed char* Asm = (signed char*)SMEM;       // 8192 B
  signed char* Bsm = Asm + 8192;               // 8192 B
  const int tid = threadIdx.x;
  const int w = tid >> 6;
  const int lane = tid & 63;
  const int wm = w & 1, wn = w >> 1;

  int b = blockIdx.x;
  int band = b / (gn * 8);
  int r = b - band * (gn * 8);
  int bm = gm - band * 8; if (bm > 8) bm = 8;
  const long m0 = ((long)band * 8 + (r % bm)) * 128;
  const long n0 = (long)(r / bm) * 128;

  const signed char* Ag = A + (m0 + 32 * w + (lane >> 2)) * (long)K + (lane & 3) * 16;
  const signed char* Bg = Bt + (n0 + 32 * w + (lane >> 2)) * (long)K + (lane & 3) * 16;
  signed char* AsmW = Asm + 32 * w * 64;
  signed char* BsmW = Bsm + 32 * w * 64;
  const long rstep = 16l * K;

  const int frow = lane & 15;
  const int fcol = (lane >> 4) * 16;

  i32x4 acc[4][4];
  i32x4 zero = {0, 0, 0, 0};
  #pragma unroll
  for (int i = 0; i < 4; ++i)
    #pragma unroll
    for (int j = 0; j < 4; ++j) acc[i][j] = zero;

  for (int kt = 0; kt < K; kt += 64) {
    __syncthreads();
    gload_lds16b(Ag + kt, AsmW);
    gload_lds16b(Ag + kt + rstep, AsmW + 16 * 64);
    gload_lds16b(Bg + kt, BsmW);
    gload_lds16b(Bg + kt + rstep, BsmW + 16 * 64);
    __syncthreads();
    i32x4 af[4], bfm[4];
    #pragma unroll
    for (int mt = 0; mt < 4; ++mt)
      af[mt] = *(const i32x4*)(Asm + (wm * 64 + mt * 16 + frow) * 64 + fcol);
    #pragma unroll
    for (int nt = 0; nt < 4; ++nt)
      bfm[nt] = *(const i32x4*)(Bsm + (wn * 64 + nt * 16 + frow) * 64 + fcol);
    #pragma unroll
    for (int mt = 0; mt < 4; ++mt)
      #pragma unroll
      for (int nt = 0; nt < 4; ++nt)
        acc[mt][nt] = __builtin_amdgcn_mfma_i32_16x16x64_i8(bfm[nt], af[mt], acc[mt][nt], 0, 0, 0);
  }

  const int nq = (lane >> 4) * 4;
  __syncthreads();   // staging LDS no longer needed; reuse as C tile
  #pragma unroll
  for (int mt = 0; mt < 4; ++mt) {
    int ml = wm * 64 + mt * 16 + frow;
    float sam = sa[m0 + ml];
    #pragma unroll
    for (int nt = 0; nt < 4; ++nt) {
      int nl = wn * 64 + nt * 16 + nq;
      float4 bv = *(const float4*)(bias + n0 + nl);
      float4 sbv = *(const float4*)(sb + n0 + nl);
      float v0 = (float)acc[mt][nt][0] * (sam * sbv.x) + bv.x;
      float v1 = (float)acc[mt][nt][1] * (sam * sbv.y) + bv.y;
      float v2 = (float)acc[mt][nt][2] * (sam * sbv.z) + bv.z;
      float v3 = (float)acc[mt][nt][3] * (sam * sbv.w) + bv.w;
      if (relu) {
        v0 = fmaxf(v0, 0.f); v1 = fmaxf(v1, 0.f);
        v2 = fmaxf(v2, 0.f); v3 = fmaxf(v3, 0.f);
      }
      u16x4 o = {f2bf(v0), f2bf(v1), f2bf(v2), f2bf(v3)};
      *(u16x4*)(SMEM + ml * 136 + nl) = o;
    }
  }
  __syncthreads();
  #pragma unroll
  for (int p = 0; p < 8; ++p) {
    int row = p * 16 + (tid >> 4);
    int col = (tid & 15) * 8;
    uint4 v = *(const uint4*)(SMEM + row * 136 + col);
    *(uint4*)(Cout + (m0 + row) * (long)N + n0 + col) = v;
  }
}

extern "C" void kernel_launch(void* const* d_in, const int* in_sizes, int n_in,
                              void* d_out, int out_size, void* d_ws, size_t ws_size,
                              hipStream_t stream) {
  (void)in_sizes; (void)n_in; (void)out_size; (void)ws_size;
  const int*   x          = (const int*)d_in[0];
  const int*   edge_index = (const int*)d_in[1];
  const int*   edge_attr  = (const int*)d_in[2];
  const int*   batch      = (const int*)d_in[3];
  const float* atom_emb1  = (const float*)d_in[4];
  const float* atom_emb2  = (const float*)d_in[5];
  const float* bond_emb1  = (const float*)d_in[6];   // [5][8][512]
  const float* bond_emb2  = (const float*)d_in[7];   // [5][4][512]
  const float* W1         = (const float*)d_in[8];   // [5][512][1024]
  const float* b1         = (const float*)d_in[9];   // [5][1024]
  const float* W2         = (const float*)d_in[10];  // [5][1024][512]
  const float* b2         = (const float*)d_in[11];  // [5][512]
  const float* pW1        = (const float*)d_in[12];  // [512][512]
  const float* pb1        = (const float*)d_in[13];
  const float* pW2        = (const float*)d_in[14];
  const float* pb2        = (const float*)d_in[15];

  // ---- workspace layout ----
  unsigned short* h      = (unsigned short*)d_ws;                 // MPAD*D bf16
  unsigned short* hidden = h + (size_t)MPAD * D;                  // MPAD*H2 bf16
  unsigned short* w2t    = hidden + (size_t)MPAD * H2;            // NL*D*H2 bf16
  unsigned short* pw1t   = w2t + (size_t)NL * D * H2;             // D*D
  unsigned short* pw2t   = pw1t + (size_t)D * D;                  // D*D
  unsigned short* pooled = pw2t + (size_t)D * D;                  // NG*D
  unsigned short* zmid   = pooled + (size_t)NG * D;               // NG*D
  signed char* aq  = (signed char*)(zmid + (size_t)NG * D);       // MPAD*512 i8
  signed char* w1q = aq + (size_t)MPAD * 512;                     // NL*H2*512 i8
  float* sa  = (float*)(w1q + (size_t)NL * H2 * 512);             // MPAD
  float* sw1 = sa + MPAD;                                         // NL*H2 (zero-init)
  int* indeg  = (int*)(sw1 + NL * H2);                            // NN+1 (zero-init)
  int* cur    = indeg + (NN + 1);                                 // NN   (zero-init)
  int* gcnt   = cur + NN;                                         // NG   (zero-init)
  int* offs   = gcnt + NG;                                        // NN+1
  int* goff   = offs + (NN + 1);                                  // NG+1
  int* packed = goff + (NG + 1);                                  // NE
  int* bsum   = packed + NE;                                      // 64

  // zero sw1 (absmax accum) + counters in one memset (adjacent)
  (void)hipMemsetAsync(sw1, 0, ((size_t)NL * H2 + (NN + 1) + NN + NG) * 4, stream);

  // W1 -> i8 [n][k] + per-col scales (split-K absmax, bit-pattern atomicMax)
  wmax_kernel<<<dim3(H2 / 256, NL, 16), 256, 0, stream>>>(W1, (unsigned*)sw1, D, H2);
  scale_kernel<<<(NL * H2 + 255) / 256, 256, 0, stream>>>((unsigned*)sw1, NL * H2);
  transpose_i8_kernel<<<dim3(H2 / 32, D / 32, NL), dim3(32, 8), 0, stream>>>(W1, w1q, sw1, D, H2);
  transpose_bf16_kernel<<<dim3(D / 32, H2 / 32, NL), dim3(32, 8), 0, stream>>>(W2, w2t, H2, D);
  transpose_bf16_kernel<<<dim3(D / 32, D / 32, 1), dim3(32, 8), 0, stream>>>(pW1, pw1t, D, D);
  transpose_bf16_kernel<<<dim3(D / 32, D / 32, 1), dim3(32, 8), 0, stream>>>(pW2, pw2t, D, D);

  atom_enc_kernel<<<(NN * 64) / 256, 256, 0, stream>>>(x, atom_emb1, atom_emb2, h);

  // CSR over dst (multi-block scan)
  const int B1 = (NN + 4095) / 4096;   // 13
  count_kernel<<<(NE + 255) / 256, 256, 0, stream>>>(edge_index + NE, indeg, NE);
  scan_sums_kernel<<<B1, 1024, 0, stream>>>(indeg, bsum, NN);
  scan_partials_kernel<<<1, 64, 0, stream>>>(bsum, B1);
  scan_final_kernel<<<B1, 1024, 0, stream>>>(indeg, bsum, offs, NN);
  fill_csr_kernel<<<(NE + 255) / 256, 256, 0, stream>>>(edge_index, edge_attr, offs, cur, packed);

  // graph ranges (batch is sorted)
  const int B2 = (NG + 4095) / 4096;   // 1
  count_kernel<<<(NN + 255) / 256, 256, 0, stream>>>(batch, gcnt, NN);
  scan_sums_kernel<<<B2, 1024, 0, stream>>>(gcnt, bsum, NG);
  scan_partials_kernel<<<1, 64, 0, stream>>>(bsum, B2);
  scan_final_kernel<<<B2, 1024, 0, stream>>>(gcnt, bsum, goff, NG);

  const int GM = MPAD / 128;  // 391
  for (int l = 0; l < NL; ++l) {
    agg_kernel<<<(NN * 64) / 256, 256, 0, stream>>>(
        h, offs, packed, bond_emb1 + (size_t)l * 8 * D, bond_emb2 + (size_t)l * 4 * D, aq, sa);
    gemm_nt_i8<<<GM * (H2 / 128), 256, 0, stream>>>(
        aq, w1q + (size_t)l * H2 * 512, sa, sw1 + (size_t)l * H2, b1 + (size_t)l * H2,
        hidden, D, H2, GM, H2 / 128, 1);
    gemm_nt<<<GM * (D / 128), 256, 0, stream>>>(
        hidden, w2t + (size_t)l * D * H2, b2 + (size_t)l * D, h,
        H2, D, GM, D / 128, (l < NL - 1) ? 1 : 0, 0);
  }

  pool_kernel<<<(NG * 64) / 256, 256, 0, stream>>>(h, goff, pooled);
  gemm_nt<<<(NG / 128) * (D / 128), 256, 0, stream>>>(
      pooled, pw1t, pb1, zmid, D, D, NG / 128, D / 128, 1, 0);
  gemm_nt<<<(NG / 128) * (D / 128), 256, 0, stream>>>(
      zmid, pw2t, pb2, (float*)d_out, D, D, NG / 128, D / 128, 0, 1);
}